// Round 4
// baseline (157.724 us; speedup 1.0000x reference)
//
#include <hip/hip_runtime.h>
#include <hip/hip_bf16.h>

typedef unsigned short u16;
typedef __attribute__((ext_vector_type(8))) short bf16x8;
typedef __attribute__((ext_vector_type(4))) float f32x4;

#define L_SEQ 2048
#define HID 1024
#define NC 32
#define MTOK 4096
#define GEPS 1e-5f
#define QSCALE 0.125f

__device__ __forceinline__ float bf2f(u16 u){ union{unsigned i; float f;}c; c.i=(unsigned)u<<16; return c.f; }
__device__ __forceinline__ u16 f2bf(float f){ union{__hip_bfloat16 h; u16 u;}c; c.h=__float2bfloat16(f); return c.u; }

__device__ __forceinline__ void gload_lds16(const u16* g, u16* l){
  __builtin_amdgcn_global_load_lds((const __attribute__((address_space(1))) void*)g,
                                   (__attribute__((address_space(3))) void*)l, 16, 0, 0);
}

// ---------------- 5x W (KxN f32) -> WT (NxK bf16), batched over z ----------------
__global__ __launch_bounds__(256) void gla_transpose5(const float* W0, const float* W1,
                                                      const float* W2, const float* W3,
                                                      const float* W4,
                                                      u16* D0, u16* D1, u16* D2, u16* D3, u16* D4){
  const float* W; u16* D;
  switch (blockIdx.z){
    case 0: W = W0; D = D0; break;
    case 1: W = W1; D = D1; break;
    case 2: W = W2; D = D2; break;
    case 3: W = W3; D = D3; break;
    default: W = W4; D = D4; break;
  }
  __shared__ float tile[32][33];
  int tx = threadIdx.x & 31, ty = threadIdx.x >> 5;
  int n0 = blockIdx.x * 32, k0 = blockIdx.y * 32;
  #pragma unroll
  for (int r = ty; r < 32; r += 8)
    tile[r][tx] = W[(size_t)(k0 + r) * HID + n0 + tx];
  __syncthreads();
  #pragma unroll
  for (int r = ty; r < 32; r += 8)
    D[(size_t)(n0 + r) * HID + k0 + tx] = f2bf(tile[tx][r]);
}

// ---------------- fused: xg1 = x @ Wg1 AND xb = bf16(x) ----------------
__global__ __launch_bounds__(256) void gla_xg1(const float* __restrict__ x,
                                               const float* __restrict__ Wg1,
                                               float* __restrict__ xg1,
                                               u16* __restrict__ xb){
  int lane = threadIdx.x & 63, wid = threadIdx.x >> 6;
  int row = blockIdx.x * 4 + wid;
  const float* xr = x + (size_t)row * HID;
  u16* xbr = xb + (size_t)row * HID;
  float acc[16];
  #pragma unroll
  for (int n = 0; n < 16; n++) acc[n] = 0.f;
  for (int k = lane; k < HID; k += 64){
    float xv = xr[k];
    xbr[k] = f2bf(xv);
    const float4* wr = (const float4*)(Wg1 + (size_t)k * 16);
    float4 w0 = wr[0], w1 = wr[1], w2 = wr[2], w3 = wr[3];
    acc[0]  += xv * w0.x; acc[1]  += xv * w0.y; acc[2]  += xv * w0.z; acc[3]  += xv * w0.w;
    acc[4]  += xv * w1.x; acc[5]  += xv * w1.y; acc[6]  += xv * w1.z; acc[7]  += xv * w1.w;
    acc[8]  += xv * w2.x; acc[9]  += xv * w2.y; acc[10] += xv * w2.z; acc[11] += xv * w2.w;
    acc[12] += xv * w3.x; acc[13] += xv * w3.y; acc[14] += xv * w3.z; acc[15] += xv * w3.w;
  }
  #pragma unroll
  for (int n = 0; n < 16; n++){
    #pragma unroll
    for (int off = 32; off > 0; off >>= 1)
      acc[n] += __shfl_down(acc[n], off, 64);
  }
  if (lane == 0){
    #pragma unroll
    for (int n = 0; n < 16; n++) xg1[(size_t)row * 16 + n] = acc[n];
  }
}

// ---------------- gate stage 2 + per-chunk cumsum: CG = cumsum_chunk(logsig/16) ----------------
__global__ __launch_bounds__(256) void gla_gkcg(const float* __restrict__ xg1,
                                                const float* __restrict__ Wg2,
                                                const float* __restrict__ bg2,
                                                float* __restrict__ CG){
  __shared__ float xs[64][16];
  int blk = blockIdx.x;
  int b = blk >> 7, r7 = blk & 127;
  int c = r7 >> 2, q = r7 & 3;
  int col = q * 256 + threadIdx.x;
  int tok0 = b * L_SEQ + c * 64;
  {
    int row = threadIdx.x >> 2, e4 = (threadIdx.x & 3) * 4;
    *(float4*)&xs[row][e4] = *(const float4*)&xg1[(size_t)(tok0 + row) * 16 + e4];
  }
  __syncthreads();
  float w[16];
  #pragma unroll
  for (int r = 0; r < 16; r++) w[r] = Wg2[r * HID + col];
  float bz = bg2[col];
  float cum = 0.f;
  for (int t = 0; t < 64; t++){
    float z = bz;
    #pragma unroll
    for (int r = 0; r < 16; r++) z += xs[t][r] * w[r];
    float ls = fminf(z, 0.f) - log1pf(__expf(-fabsf(z)));
    cum += ls * (1.0f / 16.0f);
    CG[(size_t)(tok0 + t) * HID + col] = cum;
  }
}

// ---------------- GEMM: 128-row tiles, BK=32, dbuf LDS, counted vmcnt, T2 swizzle ---------
// A (Mx1024 bf16) @ Bt (Nx1024 bf16)^T. BN in {128, 64}. SEL: bf16 out with sel-strided
// 4-way output split (QKVG); else f32 direct.
// LDS layout: [row][32 k] u16, physical_u16 = logical_u16 ^ ((row&3)<<3)  (T2, 8->4-way).
// Source pre-swizzled so gload_lds16's linear dest matches (rule 21).
template<int BN, bool SEL>
__global__ __launch_bounds__(256) void gla_gemm3(const u16* __restrict__ A,
                                                 const u16* __restrict__ Bt,
                                                 void* __restrict__ Cv){
  constexpr int AIS = 2;               // A gload issues per K-tile per thread
  constexpr int BIS = BN / 64;         // B gload issues
  constexpr int NJ  = BN / 32;         // n-frags per wave
  constexpr int NT  = HID / 32;        // K-tiles
  __shared__ u16 As[2][128 * 32];
  __shared__ u16 Bs[2][BN * 32];
  const int tid = threadIdx.x;
  const int lane = tid & 63, wid = tid >> 6;
  const int wm = wid >> 1, wn = wid & 1;
  const int lr = lane & 15, lk = lane >> 4;
  const int bm = blockIdx.x, bn = blockIdx.y;
  const int srow = tid >> 2;
  const int skw  = ((tid & 3) * 8) ^ (((tid >> 2) & 3) << 3);  // pre-swizzled k within tile
  const u16* Ag = A  + ((size_t)bm * 128 + srow) * HID + skw;
  const u16* Bg = Bt + ((size_t)bn * BN  + srow) * HID + skw;

  f32x4 acc[4][NJ];
  #pragma unroll
  for (int i = 0; i < 4; i++)
    #pragma unroll
    for (int j = 0; j < NJ; j++)
      #pragma unroll
      for (int e = 0; e < 4; e++) acc[i][j][e] = 0.f;

  auto STAGE = [&](int buf, int kt){
    #pragma unroll
    for (int i = 0; i < AIS; i++)
      gload_lds16(Ag + (size_t)(i * 64) * HID + kt * 32, &As[buf][i * 2048 + tid * 8]);
    #pragma unroll
    for (int i = 0; i < BIS; i++)
      gload_lds16(Bg + (size_t)(i * 64) * HID + kt * 32, &Bs[buf][i * 2048 + tid * 8]);
  };

  STAGE(0, 0);
  for (int t = 0; t < NT; ++t){
    const int buf = t & 1;
    if (t + 1 < NT){
      STAGE(buf ^ 1, t + 1);
      // wait only for tile t's loads (keep tile t+1's in flight across the barrier)
      if constexpr (BN == 128) asm volatile("s_waitcnt vmcnt(4)\ns_barrier" ::: "memory");
      else                     asm volatile("s_waitcnt vmcnt(3)\ns_barrier" ::: "memory");
    } else {
      asm volatile("s_waitcnt vmcnt(0)\ns_barrier" ::: "memory");
    }
    bf16x8 af[4], bfr[NJ];
    #pragma unroll
    for (int m = 0; m < 4; m++){
      int row = wm * 64 + m * 16 + lr;
      af[m] = *(const bf16x8*)&As[buf][(row * 32 + lk * 8) ^ ((row & 3) << 3)];
    }
    #pragma unroll
    for (int n = 0; n < NJ; n++){
      int row = wn * (BN / 2) + n * 16 + lr;
      bfr[n] = *(const bf16x8*)&Bs[buf][(row * 32 + lk * 8) ^ ((row & 3) << 3)];
    }
    __builtin_amdgcn_s_setprio(1);
    #pragma unroll
    for (int m = 0; m < 4; m++)
      #pragma unroll
      for (int n = 0; n < NJ; n++)
        acc[m][n] = __builtin_amdgcn_mfma_f32_16x16x32_bf16(af[m], bfr[n], acc[m][n], 0, 0, 0);
    __builtin_amdgcn_s_setprio(0);
    __builtin_amdgcn_sched_barrier(0);
    asm volatile("s_barrier" ::: "memory");   // reads of buf done before next STAGE overwrites
  }

  #pragma unroll
  for (int i = 0; i < 4; i++)
    #pragma unroll
    for (int j = 0; j < NJ; j++){
      int row0 = bm * 128 + wm * 64 + i * 16 + lk * 4;
      int cb   = bn * BN + wn * (BN / 2) + j * 16 + lr;
      if constexpr (SEL){
        u16* C = (u16*)Cv;
        int sel = cb >> 10, col = cb & 1023;
        size_t base = (size_t)sel * ((size_t)MTOK * HID) + (size_t)row0 * HID + col;
        #pragma unroll
        for (int r = 0; r < 4; r++)
          C[base + (size_t)r * HID] = f2bf(acc[i][j][r]);
      } else {
        float* C = (float*)Cv;
        #pragma unroll
        for (int r = 0; r < 4; r++)
          C[(size_t)(row0 + r) * HID + cb] = acc[i][j][r];
      }
    }
}

// ---------------- pass B (MFMA): T_c = K^hat^T @ V, D_c = exp(cg_last) ----------------
__global__ __launch_bounds__(256) void gla_chunk_state2(const u16* __restrict__ Kb,
                                                        const u16* __restrict__ Vb,
                                                        const float* __restrict__ CG,
                                                        float* __restrict__ Tbuf,
                                                        float* __restrict__ Dbuf){
  __shared__ u16 KHT[64 * 72];   // K^hat transposed: rows d, k = t
  __shared__ u16 VT[64 * 72];    // V transposed: rows v, k = t
  int blk = blockIdx.x;
  int c = blk & (NC - 1), bh = blk >> 5;
  int b = bh >> 4, h = bh & 15;
  int tid = threadIdx.x;
  int lane = tid & 63, w = tid >> 6;
  int lr = lane & 15, lk = lane >> 4;
  int tr = tid >> 2, tc = (tid & 3) * 16;
  size_t gbase = ((size_t)(b * L_SEQ + c * 64)) * HID + h * 64;

  float cg[16], cgl[16];
  {
    const float* cgp = CG + gbase + (size_t)tr * HID + tc;
    const float* clp = CG + gbase + (size_t)63 * HID + tc;
    #pragma unroll
    for (int j = 0; j < 16; j += 4){
      float4 a4 = *(const float4*)(cgp + j);
      float4 l4 = *(const float4*)(clp + j);
      cg[j] = a4.x; cg[j+1] = a4.y; cg[j+2] = a4.z; cg[j+3] = a4.w;
      cgl[j] = l4.x; cgl[j+1] = l4.y; cgl[j+2] = l4.z; cgl[j+3] = l4.w;
    }
  }
  {
    const u16* kp = Kb + gbase + (size_t)tr * HID + tc;
    const u16* vp = Vb + gbase + (size_t)tr * HID + tc;
    uint4 kr0 = *(const uint4*)kp, kr1 = *(const uint4*)(kp + 8);
    uint4 vr0 = *(const uint4*)vp, vr1 = *(const uint4*)(vp + 8);
    const u16* ku = (const u16*)&kr0; const u16* ku2 = (const u16*)&kr1;
    const u16* vu = (const u16*)&vr0; const u16* vu2 = (const u16*)&vr1;
    #pragma unroll
    for (int e = 0; e < 8; e++){
      KHT[(tc + e) * 72 + tr]     = f2bf(bf2f(ku[e])  * __expf(cgl[e]     - cg[e]));
      KHT[(tc + 8 + e) * 72 + tr] = f2bf(bf2f(ku2[e]) * __expf(cgl[8 + e] - cg[8 + e]));
      VT[(tc + e) * 72 + tr]      = vu[e];
      VT[(tc + 8 + e) * 72 + tr]  = vu2[e];
    }
  }
  if (tr == 0){
    #pragma unroll
    for (int e = 0; e < 16; e++)
      Dbuf[(size_t)blk * 64 + tc + e] = __expf(cgl[e]);
  }
  __syncthreads();
  int R0 = w * 16;
  f32x4 tacc[4];
  #pragma unroll
  for (int v = 0; v < 4; v++)
    #pragma unroll
    for (int e = 0; e < 4; e++) tacc[v][e] = 0.f;
  #pragma unroll
  for (int ks = 0; ks < 2; ks++){
    bf16x8 a = *(const bf16x8*)&KHT[(R0 + lr) * 72 + ks * 32 + lk * 8];
    #pragma unroll
    for (int v0 = 0; v0 < 4; v0++){
      bf16x8 bb = *(const bf16x8*)&VT[(v0 * 16 + lr) * 72 + ks * 32 + lk * 8];
      tacc[v0] = __builtin_amdgcn_mfma_f32_16x16x32_bf16(a, bb, tacc[v0], 0, 0, 0);
    }
  }
  #pragma unroll
  for (int v0 = 0; v0 < 4; v0++){
    int d = R0 + lk * 4, v = v0 * 16 + lr;
    #pragma unroll
    for (int r = 0; r < 4; r++)
      Tbuf[(size_t)blk * 4096 + (size_t)(d + r) * 64 + v] = tacc[v0][r];
  }
}

// ---------------- pass C: parallel chunk-state scan; S_in emitted bf16 ----------------
__global__ __launch_bounds__(256) void gla_state_scan2(const float* __restrict__ Tbuf,
                                                       const float* __restrict__ Dbuf,
                                                       float* __restrict__ Sfin,
                                                       u16* __restrict__ Sinb){
  int bh = blockIdx.x >> 4, seg = blockIdx.x & 15;
  int dv = seg * 256 + threadIdx.x;
  int d = dv >> 6;
  float S = 0.f;
  for (int c = 0; c < NC; c++){
    size_t slot = (size_t)bh * NC + c;
    float t  = Tbuf[slot * 4096 + dv];
    float dec = Dbuf[slot * 64 + d];
    Sinb[slot * 4096 + dv] = f2bf(S);
    S = dec * S + t;
  }
  Sfin[(size_t)bh * 4096 + dv] = S;
}

// ---------------- pass D (MFMA): outputs + RMSNorm + swish gate ----------------
__global__ __launch_bounds__(256) void gla_chunk_out2(const u16* __restrict__ Qb,
                                                      const u16* __restrict__ Kb,
                                                      const u16* __restrict__ Vb,
                                                      const float* __restrict__ CG,
                                                      const u16* __restrict__ Sinb,
                                                      const u16* __restrict__ Gb,
                                                      const float* __restrict__ gnw,
                                                      u16* __restrict__ OG){
  __shared__ u16 QT[64 * 72];   // q~ rows t, k=d
  __shared__ u16 KT[64 * 72];   // k~ rows j, k=d ; reused for gate after matmul1
  __shared__ u16 VT[64 * 72];   // V^T rows v, k=t
  __shared__ u16 ST[64 * 72];   // S_in^T rows v, k=d ; reused for output staging
  __shared__ u16 PS[64 * 72];   // masked P rows t, k=j
  int blk = blockIdx.x;
  int c = blk & (NC - 1), bh = blk >> 5;
  int b = bh >> 4, h = bh & 15;
  int tid = threadIdx.x;
  int lane = tid & 63, w = tid >> 6;
  int lr = lane & 15, lk = lane >> 4;
  int tr = tid >> 2, tc = (tid & 3) * 16;
  size_t gbase = ((size_t)(b * L_SEQ + c * 64)) * HID + h * 64;

  // ---- stage q~, k~, V^T, S^T ----
  {
    float cg[16];
    const float* cgp = CG + gbase + (size_t)tr * HID + tc;
    #pragma unroll
    for (int j = 0; j < 16; j += 4){
      float4 a4 = *(const float4*)(cgp + j);
      cg[j] = a4.x; cg[j+1] = a4.y; cg[j+2] = a4.z; cg[j+3] = a4.w;
    }
    const u16* qp = Qb + gbase + (size_t)tr * HID + tc;
    const u16* kp = Kb + gbase + (size_t)tr * HID + tc;
    const u16* vp = Vb + gbase + (size_t)tr * HID + tc;
    uint4 qr0 = *(const uint4*)qp, qr1 = *(const uint4*)(qp + 8);
    uint4 kr0 = *(const uint4*)kp, kr1 = *(const uint4*)(kp + 8);
    uint4 vr0 = *(const uint4*)vp, vr1 = *(const uint4*)(vp + 8);
    const u16* qu = (const u16*)&qr0; const u16* qu2 = (const u16*)&qr1;
    const u16* ku = (const u16*)&kr0; const u16* ku2 = (const u16*)&kr1;
    const u16* vu = (const u16*)&vr0; const u16* vu2 = (const u16*)&vr1;
    u16 qt[16] __attribute__((aligned(16)));
    u16 kt[16] __attribute__((aligned(16)));
    #pragma unroll
    for (int e = 0; e < 8; e++){
      float ec0 = __expf(cg[e]),  ei0 = __expf(-cg[e]);
      float ec1 = __expf(cg[8+e]), ei1 = __expf(-cg[8+e]);
      qt[e]     = f2bf(bf2f(qu[e])  * ec0 * QSCALE);
      qt[8 + e] = f2bf(bf2f(qu2[e]) * ec1 * QSCALE);
      kt[e]     = f2bf(bf2f(ku[e])  * ei0);
      kt[8 + e] = f2bf(bf2f(ku2[e]) * ei1);
      VT[(tc + e) * 72 + tr]     = vu[e];
      VT[(tc + 8 + e) * 72 + tr] = vu2[e];
    }
    *(uint4*)&QT[tr * 72 + tc]     = *(uint4*)&qt[0];
    *(uint4*)&QT[tr * 72 + tc + 8] = *(uint4*)&qt[8];
    *(uint4*)&KT[tr * 72 + tc]     = *(uint4*)&kt[0];
    *(uint4*)&KT[tr * 72 + tc + 8] = *(uint4*)&kt[8];
    const u16* sp = Sinb + (size_t)blk * 4096 + (size_t)tr * 64 + tc;
    uint4 s0 = *(const uint4*)sp, s1 = *(const uint4*)(sp + 8);
    const u16* su = (const u16*)&s0; const u16* su2 = (const u16*)&s1;
    #pragma unroll
    for (int e = 0; e < 8; e++){
      ST[(tc + e) * 72 + tr]     = su[e];
      ST[(tc + 8 + e) * 72 + tr] = su2[e];
    }
  }
  __syncthreads();

  // ---- matmul 1: P = q~ @ k~^T, masked, -> PS (bf16) ----
  int R0 = w * 16;
  {
    f32x4 pacc[4];
    #pragma unroll
    for (int j = 0; j < 4; j++)
      #pragma unroll
      for (int e = 0; e < 4; e++) pacc[j][e] = 0.f;
    #pragma unroll
    for (int ks = 0; ks < 2; ks++){
      bf16x8 a = *(const bf16x8*)&QT[(R0 + lr) * 72 + ks * 32 + lk * 8];
      #pragma unroll
      for (int j0 = 0; j0 < 4; j0++){
        bf16x8 bb = *(const bf16x8*)&KT[(j0 * 16 + lr) * 72 + ks * 32 + lk * 8];
        pacc[j0] = __builtin_amdgcn_mfma_f32_16x16x32_bf16(a, bb, pacc[j0], 0, 0, 0);
      }
    }
    #pragma unroll
    for (int j0 = 0; j0 < 4; j0++){
      int j = j0 * 16 + lr;
      #pragma unroll
      for (int r = 0; r < 4; r++){
        int t = R0 + lk * 4 + r;
        PS[t * 72 + j] = (j <= t) ? f2bf(pacc[j0][r]) : (u16)0;
      }
    }
  }
  __syncthreads();

  // ---- stage gate into KT space; matmul 3 (q~ @ S^T) + matmul 2 (P @ V^T) ----
  uint4 gr0, gr1;
  {
    const u16* gp = Gb + gbase + (size_t)tr * HID + tc;
    gr0 = *(const uint4*)gp; gr1 = *(const uint4*)(gp + 8);
  }
  f32x4 oacc[4];
  #pragma unroll
  for (int v = 0; v < 4; v++)
    #pragma unroll
    for (int e = 0; e < 4; e++) oacc[v][e] = 0.f;
  #pragma unroll
  for (int ks = 0; ks < 2; ks++){
    bf16x8 a = *(const bf16x8*)&QT[(R0 + lr) * 72 + ks * 32 + lk * 8];
    #pragma unroll
    for (int v0 = 0; v0 < 4; v0++){
      bf16x8 bb = *(const bf16x8*)&ST[(v0 * 16 + lr) * 72 + ks * 32 + lk * 8];
      oacc[v0] = __builtin_amdgcn_mfma_f32_16x16x32_bf16(a, bb, oacc[v0], 0, 0, 0);
    }
  }
  #pragma unroll
  for (int ks = 0; ks < 2; ks++){
    bf16x8 a = *(const bf16x8*)&PS[(R0 + lr) * 72 + ks * 32 + lk * 8];
    #pragma unroll
    for (int v0 = 0; v0 < 4; v0++){
      bf16x8 bb = *(const bf16x8*)&VT[(v0 * 16 + lr) * 72 + ks * 32 + lk * 8];
      oacc[v0] = __builtin_amdgcn_mfma_f32_16x16x32_bf16(a, bb, oacc[v0], 0, 0, 0);
    }
  }
  *(uint4*)&KT[tr * 72 + tc]     = gr0;   // gate
  *(uint4*)&KT[tr * 72 + tc + 8] = gr1;
  __syncthreads();

  // ---- epilogue: RMSNorm over v, affine, swish gate; stage to ST then coalesced out ----
  {
    float gnv[4];
    #pragma unroll
    for (int v0 = 0; v0 < 4; v0++) gnv[v0] = gnw[v0 * 16 + lr];
    #pragma unroll
    for (int r = 0; r < 4; r++){
      float ssq = 0.f;
      #pragma unroll
      for (int v0 = 0; v0 < 4; v0++) ssq += oacc[v0][r] * oacc[v0][r];
      ssq += __shfl_xor(ssq, 1, 64);
      ssq += __shfl_xor(ssq, 2, 64);
      ssq += __shfl_xor(ssq, 4, 64);
      ssq += __shfl_xor(ssq, 8, 64);
      float rn = rsqrtf(ssq * (1.0f / 64.0f) + GEPS);
      int t = R0 + lk * 4 + r;
      #pragma unroll
      for (int v0 = 0; v0 < 4; v0++){
        float g = bf2f(KT[t * 72 + v0 * 16 + lr]);
        float sw = g / (1.f + __expf(-g));
        ST[t * 72 + v0 * 16 + lr] = f2bf(oacc[v0][r] * rn * gnv[v0] * sw);
      }
    }
  }
  __syncthreads();
  {
    uint4 o0 = *(uint4*)&ST[tr * 72 + tc];
    uint4 o1 = *(uint4*)&ST[tr * 72 + tc + 8];
    u16* op = OG + gbase + (size_t)tr * HID + tc;
    *(uint4*)op       = o0;
    *(uint4*)(op + 8) = o1;
  }
}

// ---------------- host launcher ----------------
extern "C" void kernel_launch(void* const* d_in, const int* in_sizes, int n_in,
                              void* d_out, int out_size, void* d_ws, size_t ws_size,
                              hipStream_t stream){
  (void)in_sizes; (void)n_in; (void)out_size;
  const float* x   = (const float*)d_in[0];
  const float* Wq  = (const float*)d_in[1];
  const float* Wk  = (const float*)d_in[2];
  const float* Wv  = (const float*)d_in[3];
  const float* Wg1 = (const float*)d_in[4];
  const float* Wg2 = (const float*)d_in[5];
  const float* bg2 = (const float*)d_in[6];
  const float* Wg  = (const float*)d_in[7];
  const float* gnw = (const float*)d_in[8];
  const float* Wo  = (const float*)d_in[9];
  float* out = (float*)d_out;

  char* ws = (char*)d_ws;
  size_t off = 0;
  auto alloc = [&](size_t bytes) -> char* {
    char* p = ws + off; off += (bytes + 255) & ~(size_t)255; return p;
  };
  u16* xb   = (u16*)alloc((size_t)MTOK * HID * 2);
  u16* WTq  = (u16*)alloc((size_t)HID * HID * 2);   // WTq..WTg contiguous: combined N=4096
  u16* WTk  = (u16*)alloc((size_t)HID * HID * 2);
  u16* WTv  = (u16*)alloc((size_t)HID * HID * 2);
  u16* WTg  = (u16*)alloc((size_t)HID * HID * 2);
  u16* WTo  = (u16*)alloc((size_t)HID * HID * 2);
  u16* Qb   = (u16*)alloc((size_t)MTOK * HID * 2);  // Qb..Gb contiguous: sel-strided C
  u16* Kb   = (u16*)alloc((size_t)MTOK * HID * 2);
  u16* Vb   = (u16*)alloc((size_t)MTOK * HID * 2);
  u16* Gb   = (u16*)alloc((size_t)MTOK * HID * 2);
  float* CGb  = (float*)alloc((size_t)MTOK * HID * 4);
  float* xg1b = (float*)alloc((size_t)MTOK * 16 * 4);
  float* Tbuf = (float*)alloc((size_t)1024 * 4096 * 4);
  float* Dbuf = (float*)alloc((size_t)1024 * 64 * 4);
  u16* Sinb = (u16*)alloc((size_t)1024 * 4096 * 2);
  u16* OG   = (u16*)alloc((size_t)MTOK * HID * 2);
  if (off > ws_size) return;

  gla_xg1<<<1024, 256, 0, stream>>>(x, Wg1, xg1b, xb);
  dim3 tg(32, 32, 5);
  gla_transpose5<<<tg, 256, 0, stream>>>(Wq, Wk, Wv, Wg, Wo, WTq, WTk, WTv, WTg, WTo);
  gla_gkcg<<<256, 256, 0, stream>>>(xg1b, Wg2, bg2, CGb);

  dim3 gq(32, 32);
  gla_gemm3<128, true><<<gq, 256, 0, stream>>>(xb, WTq, Qb);   // Q,K,V,G in one dispatch

  gla_chunk_state2<<<1024, 256, 0, stream>>>(Kb, Vb, CGb, Tbuf, Dbuf);
  gla_state_scan2<<<512, 256, 0, stream>>>(Tbuf, Dbuf, out + (size_t)MTOK * HID, Sinb);
  gla_chunk_out2<<<1024, 256, 0, stream>>>(Qb, Kb, Vb, CGb, Sinb, Gb, gnw, OG);

  dim3 go(32, 16);
  gla_gemm3<64, false><<<go, 256, 0, stream>>>(OG, WTo, out);
}

// Round 5
// 150.249 us; speedup vs baseline: 1.0497x; 1.0497x over previous
//
#include <hip/hip_runtime.h>
#include <hip/hip_bf16.h>

typedef unsigned short u16;
typedef __attribute__((ext_vector_type(8))) short bf16x8;
typedef __attribute__((ext_vector_type(4))) float f32x4;

#define L_SEQ 2048
#define HID 1024
#define NC 32
#define MTOK 4096
#define GEPS 1e-5f
#define QSCALE 0.125f

__device__ __forceinline__ float bf2f(u16 u){ union{unsigned i; float f;}c; c.i=(unsigned)u<<16; return c.f; }
__device__ __forceinline__ u16 f2bf(float f){ union{__hip_bfloat16 h; u16 u;}c; c.h=__float2bfloat16(f); return c.u; }

__device__ __forceinline__ void gload_lds16(const u16* g, u16* l){
  __builtin_amdgcn_global_load_lds((const __attribute__((address_space(1))) void*)g,
                                   (__attribute__((address_space(3))) void*)l, 16, 0, 0);
}

// ---------------- 5x W (KxN f32) -> WT (NxK bf16), batched over z ----------------
__global__ __launch_bounds__(256) void gla_transpose5(const float* W0, const float* W1,
                                                      const float* W2, const float* W3,
                                                      const float* W4,
                                                      u16* D0, u16* D1, u16* D2, u16* D3, u16* D4){
  const float* W; u16* D;
  switch (blockIdx.z){
    case 0: W = W0; D = D0; break;
    case 1: W = W1; D = D1; break;
    case 2: W = W2; D = D2; break;
    case 3: W = W3; D = D3; break;
    default: W = W4; D = D4; break;
  }
  __shared__ float tile[32][33];
  int tx = threadIdx.x & 31, ty = threadIdx.x >> 5;
  int n0 = blockIdx.x * 32, k0 = blockIdx.y * 32;
  #pragma unroll
  for (int r = ty; r < 32; r += 8)
    tile[r][tx] = W[(size_t)(k0 + r) * HID + n0 + tx];
  __syncthreads();
  #pragma unroll
  for (int r = ty; r < 32; r += 8)
    D[(size_t)(n0 + r) * HID + k0 + tx] = f2bf(tile[tx][r]);
}

// ---------------- fused: xg1 = x @ Wg1 AND xb = bf16(x) ----------------
__global__ __launch_bounds__(256) void gla_xg1(const float* __restrict__ x,
                                               const float* __restrict__ Wg1,
                                               float* __restrict__ xg1,
                                               u16* __restrict__ xb){
  int lane = threadIdx.x & 63, wid = threadIdx.x >> 6;
  int row = blockIdx.x * 4 + wid;
  const float* xr = x + (size_t)row * HID;
  u16* xbr = xb + (size_t)row * HID;
  float acc[16];
  #pragma unroll
  for (int n = 0; n < 16; n++) acc[n] = 0.f;
  for (int k = lane; k < HID; k += 64){
    float xv = xr[k];
    xbr[k] = f2bf(xv);
    const float4* wr = (const float4*)(Wg1 + (size_t)k * 16);
    float4 w0 = wr[0], w1 = wr[1], w2 = wr[2], w3 = wr[3];
    acc[0]  += xv * w0.x; acc[1]  += xv * w0.y; acc[2]  += xv * w0.z; acc[3]  += xv * w0.w;
    acc[4]  += xv * w1.x; acc[5]  += xv * w1.y; acc[6]  += xv * w1.z; acc[7]  += xv * w1.w;
    acc[8]  += xv * w2.x; acc[9]  += xv * w2.y; acc[10] += xv * w2.z; acc[11] += xv * w2.w;
    acc[12] += xv * w3.x; acc[13] += xv * w3.y; acc[14] += xv * w3.z; acc[15] += xv * w3.w;
  }
  #pragma unroll
  for (int n = 0; n < 16; n++){
    #pragma unroll
    for (int off = 32; off > 0; off >>= 1)
      acc[n] += __shfl_down(acc[n], off, 64);
  }
  if (lane == 0){
    #pragma unroll
    for (int n = 0; n < 16; n++) xg1[(size_t)row * 16 + n] = acc[n];
  }
}

// ---------------- gate stage 2 + per-chunk cumsum: CG (bf16) ----------------
__global__ __launch_bounds__(256) void gla_gkcg(const float* __restrict__ xg1,
                                                const float* __restrict__ Wg2,
                                                const float* __restrict__ bg2,
                                                u16* __restrict__ CG){
  __shared__ float xs[64][16];
  int blk = blockIdx.x;
  int b = blk >> 7, r7 = blk & 127;
  int c = r7 >> 2, q = r7 & 3;
  int col = q * 256 + threadIdx.x;
  int tok0 = b * L_SEQ + c * 64;
  {
    int row = threadIdx.x >> 2, e4 = (threadIdx.x & 3) * 4;
    *(float4*)&xs[row][e4] = *(const float4*)&xg1[(size_t)(tok0 + row) * 16 + e4];
  }
  __syncthreads();
  float w[16];
  #pragma unroll
  for (int r = 0; r < 16; r++) w[r] = Wg2[r * HID + col];
  float bz = bg2[col];
  float cum = 0.f;
  for (int t = 0; t < 64; t++){
    float z = bz;
    #pragma unroll
    for (int r = 0; r < 16; r++) z += xs[t][r] * w[r];
    float ls = fminf(z, 0.f) - log1pf(__expf(-fabsf(z)));
    cum += ls * (1.0f / 16.0f);
    CG[(size_t)(tok0 + t) * HID + col] = f2bf(cum);
  }
}

// ---------------- QKVG GEMM: 256x128 tile, 512 thr / 8 waves, dbuf + counted vmcnt ------
// A (4096x1024 bf16) @ Bt (4096x1024 bf16)^T -> 4 bf16 outputs (sel-strided).
// LDS swizzle: physical_u16 = logical ^ ((row&3)<<3); source pre-swizzled (rule 21).
__global__ __launch_bounds__(512) void gla_gemm_qkvg(const u16* __restrict__ A,
                                                     const u16* __restrict__ Bt,
                                                     u16* __restrict__ C){
  constexpr int NT = HID / 32;
  __shared__ u16 As[2][256 * 32];
  __shared__ u16 Bs[2][128 * 32];
  const int tid = threadIdx.x;
  const int lane = tid & 63, wid = tid >> 6;       // 8 waves
  const int wm = wid >> 1, wn = wid & 1;           // 4m x 2n, wave tile 64x64
  const int lr = lane & 15, lk = lane >> 4;
  const int bm = blockIdx.x, bn = blockIdx.y;      // 16 x 32
  const int srow = tid >> 2;                       // 0..127
  const int skw  = ((tid & 3) * 8) ^ ((srow & 3) << 3);
  const u16* Ag = A  + ((size_t)bm * 256 + srow) * HID + skw;
  const u16* Bg = Bt + ((size_t)bn * 128 + srow) * HID + skw;

  f32x4 acc[4][4];
  #pragma unroll
  for (int i = 0; i < 4; i++)
    #pragma unroll
    for (int j = 0; j < 4; j++)
      #pragma unroll
      for (int e = 0; e < 4; e++) acc[i][j][e] = 0.f;

  auto STAGE = [&](int buf, int kt){
    gload_lds16(Ag + kt * 32,                         &As[buf][tid * 8]);
    gload_lds16(Ag + (size_t)128 * HID + kt * 32,     &As[buf][4096 + tid * 8]);
    gload_lds16(Bg + kt * 32,                         &Bs[buf][tid * 8]);
  };

  STAGE(0, 0);
  for (int t = 0; t < NT; ++t){
    const int buf = t & 1;
    if (t + 1 < NT){
      STAGE(buf ^ 1, t + 1);
      asm volatile("s_waitcnt vmcnt(3)\ns_barrier" ::: "memory");
    } else {
      asm volatile("s_waitcnt vmcnt(0)\ns_barrier" ::: "memory");
    }
    bf16x8 af[4], bfr[4];
    #pragma unroll
    for (int m = 0; m < 4; m++){
      int row = wm * 64 + m * 16 + lr;
      af[m] = *(const bf16x8*)&As[buf][(row * 32 + lk * 8) ^ ((row & 3) << 3)];
    }
    #pragma unroll
    for (int n = 0; n < 4; n++){
      int row = wn * 64 + n * 16 + lr;
      bfr[n] = *(const bf16x8*)&Bs[buf][(row * 32 + lk * 8) ^ ((row & 3) << 3)];
    }
    __builtin_amdgcn_s_setprio(1);
    #pragma unroll
    for (int m = 0; m < 4; m++)
      #pragma unroll
      for (int n = 0; n < 4; n++)
        acc[m][n] = __builtin_amdgcn_mfma_f32_16x16x32_bf16(af[m], bfr[n], acc[m][n], 0, 0, 0);
    __builtin_amdgcn_s_setprio(0);
    __builtin_amdgcn_sched_barrier(0);
    asm volatile("s_barrier" ::: "memory");
  }

  #pragma unroll
  for (int i = 0; i < 4; i++)
    #pragma unroll
    for (int j = 0; j < 4; j++){
      int row0 = bm * 256 + wm * 64 + i * 16 + lk * 4;
      int cb   = bn * 128 + wn * 64 + j * 16 + lr;
      int sel  = cb >> 10, col = cb & 1023;
      size_t base = (size_t)sel * ((size_t)MTOK * HID) + (size_t)row0 * HID + col;
      #pragma unroll
      for (int r = 0; r < 4; r++)
        C[base + (size_t)r * HID] = f2bf(acc[i][j][r]);
    }
}

// ---------------- out GEMM split-K=2: 128x128 tile, K=512 per z; f32 partials ----------
__global__ __launch_bounds__(256) void gla_gemm_ws(const u16* __restrict__ A,
                                                   const u16* __restrict__ Bt,
                                                   float* __restrict__ P){
  constexpr int NT = 16;                 // 512 / 32
  __shared__ u16 As[2][128 * 32];
  __shared__ u16 Bs[2][128 * 32];
  const int tid = threadIdx.x;
  const int lane = tid & 63, wid = tid >> 6;
  const int wm = wid >> 1, wn = wid & 1;
  const int lr = lane & 15, lk = lane >> 4;
  const int bm = blockIdx.x, bn = blockIdx.y;
  const int koff = blockIdx.z * 512;
  const int srow = tid >> 2;
  const int skw  = ((tid & 3) * 8) ^ ((srow & 3) << 3);
  const u16* Ag = A  + ((size_t)bm * 128 + srow) * HID + koff + skw;
  const u16* Bg = Bt + ((size_t)bn * 128 + srow) * HID + koff + skw;
  float* Pz = P + (size_t)blockIdx.z * MTOK * HID;

  f32x4 acc[4][4];
  #pragma unroll
  for (int i = 0; i < 4; i++)
    #pragma unroll
    for (int j = 0; j < 4; j++)
      #pragma unroll
      for (int e = 0; e < 4; e++) acc[i][j][e] = 0.f;

  auto STAGE = [&](int buf, int kt){
    gload_lds16(Ag + kt * 32,                      &As[buf][tid * 8]);
    gload_lds16(Ag + (size_t)64 * HID + kt * 32,   &As[buf][2048 + tid * 8]);
    gload_lds16(Bg + kt * 32,                      &Bs[buf][tid * 8]);
    gload_lds16(Bg + (size_t)64 * HID + kt * 32,   &Bs[buf][2048 + tid * 8]);
  };

  STAGE(0, 0);
  for (int t = 0; t < NT; ++t){
    const int buf = t & 1;
    if (t + 1 < NT){
      STAGE(buf ^ 1, t + 1);
      asm volatile("s_waitcnt vmcnt(4)\ns_barrier" ::: "memory");
    } else {
      asm volatile("s_waitcnt vmcnt(0)\ns_barrier" ::: "memory");
    }
    bf16x8 af[4], bfr[4];
    #pragma unroll
    for (int m = 0; m < 4; m++){
      int row = wm * 64 + m * 16 + lr;
      af[m] = *(const bf16x8*)&As[buf][(row * 32 + lk * 8) ^ ((row & 3) << 3)];
    }
    #pragma unroll
    for (int n = 0; n < 4; n++){
      int row = wn * 64 + n * 16 + lr;
      bfr[n] = *(const bf16x8*)&Bs[buf][(row * 32 + lk * 8) ^ ((row & 3) << 3)];
    }
    __builtin_amdgcn_s_setprio(1);
    #pragma unroll
    for (int m = 0; m < 4; m++)
      #pragma unroll
      for (int n = 0; n < 4; n++)
        acc[m][n] = __builtin_amdgcn_mfma_f32_16x16x32_bf16(af[m], bfr[n], acc[m][n], 0, 0, 0);
    __builtin_amdgcn_s_setprio(0);
    __builtin_amdgcn_sched_barrier(0);
    asm volatile("s_barrier" ::: "memory");
  }

  #pragma unroll
  for (int i = 0; i < 4; i++)
    #pragma unroll
    for (int j = 0; j < 4; j++){
      int row0 = bm * 128 + wm * 64 + i * 16 + lk * 4;
      int col  = bn * 128 + wn * 64 + j * 16 + lr;
      #pragma unroll
      for (int r = 0; r < 4; r++)
        Pz[(size_t)(row0 + r) * HID + col] = acc[i][j][r];
    }
}

// ---------------- combine split-K partials ----------------
__global__ __launch_bounds__(256) void gla_add2(const float* __restrict__ P,
                                                float* __restrict__ out){
  size_t i = ((size_t)blockIdx.x * 256 + threadIdx.x) * 4;
  float4 a = *(const float4*)&P[i];
  float4 b = *(const float4*)&P[(size_t)MTOK * HID + i];
  float4 o; o.x = a.x + b.x; o.y = a.y + b.y; o.z = a.z + b.z; o.w = a.w + b.w;
  *(float4*)&out[i] = o;
}

// ---------------- pass B (MFMA): T_c = K^hat^T @ V, D_c = exp(cg_last) ----------------
__global__ __launch_bounds__(256) void gla_chunk_state2(const u16* __restrict__ Kb,
                                                        const u16* __restrict__ Vb,
                                                        const u16* __restrict__ CG,
                                                        float* __restrict__ Tbuf,
                                                        float* __restrict__ Dbuf){
  __shared__ u16 KHT[64 * 72];   // K^hat transposed: rows d, k = t
  __shared__ u16 VT[64 * 72];    // V transposed: rows v, k = t
  int blk = blockIdx.x;
  int c = blk & (NC - 1), bh = blk >> 5;
  int b = bh >> 4, h = bh & 15;
  int tid = threadIdx.x;
  int lane = tid & 63, w = tid >> 6;
  int lr = lane & 15, lk = lane >> 4;
  int tr = tid >> 2, tc = (tid & 3) * 16;
  size_t gbase = ((size_t)(b * L_SEQ + c * 64)) * HID + h * 64;

  float cg[16], cgl[16];
  {
    const u16* cgp = CG + gbase + (size_t)tr * HID + tc;
    const u16* clp = CG + gbase + (size_t)63 * HID + tc;
    uint4 a0 = *(const uint4*)cgp, a1 = *(const uint4*)(cgp + 8);
    uint4 l0 = *(const uint4*)clp, l1 = *(const uint4*)(clp + 8);
    const u16* au = (const u16*)&a0; const u16* au2 = (const u16*)&a1;
    const u16* lu = (const u16*)&l0; const u16* lu2 = (const u16*)&l1;
    #pragma unroll
    for (int e = 0; e < 8; e++){
      cg[e] = bf2f(au[e]); cg[8 + e] = bf2f(au2[e]);
      cgl[e] = bf2f(lu[e]); cgl[8 + e] = bf2f(lu2[e]);
    }
  }
  {
    const u16* kp = Kb + gbase + (size_t)tr * HID + tc;
    const u16* vp = Vb + gbase + (size_t)tr * HID + tc;
    uint4 kr0 = *(const uint4*)kp, kr1 = *(const uint4*)(kp + 8);
    uint4 vr0 = *(const uint4*)vp, vr1 = *(const uint4*)(vp + 8);
    const u16* ku = (const u16*)&kr0; const u16* ku2 = (const u16*)&kr1;
    const u16* vu = (const u16*)&vr0; const u16* vu2 = (const u16*)&vr1;
    #pragma unroll
    for (int e = 0; e < 8; e++){
      KHT[(tc + e) * 72 + tr]     = f2bf(bf2f(ku[e])  * __expf(cgl[e]     - cg[e]));
      KHT[(tc + 8 + e) * 72 + tr] = f2bf(bf2f(ku2[e]) * __expf(cgl[8 + e] - cg[8 + e]));
      VT[(tc + e) * 72 + tr]      = vu[e];
      VT[(tc + 8 + e) * 72 + tr]  = vu2[e];
    }
  }
  if (tr == 0){
    #pragma unroll
    for (int e = 0; e < 16; e++)
      Dbuf[(size_t)blk * 64 + tc + e] = __expf(cgl[e]);
  }
  __syncthreads();
  int R0 = w * 16;
  f32x4 tacc[4];
  #pragma unroll
  for (int v = 0; v < 4; v++)
    #pragma unroll
    for (int e = 0; e < 4; e++) tacc[v][e] = 0.f;
  #pragma unroll
  for (int ks = 0; ks < 2; ks++){
    bf16x8 a = *(const bf16x8*)&KHT[(R0 + lr) * 72 + ks * 32 + lk * 8];
    #pragma unroll
    for (int v0 = 0; v0 < 4; v0++){
      bf16x8 bb = *(const bf16x8*)&VT[(v0 * 16 + lr) * 72 + ks * 32 + lk * 8];
      tacc[v0] = __builtin_amdgcn_mfma_f32_16x16x32_bf16(a, bb, tacc[v0], 0, 0, 0);
    }
  }
  #pragma unroll
  for (int v0 = 0; v0 < 4; v0++){
    int d = R0 + lk * 4, v = v0 * 16 + lr;
    #pragma unroll
    for (int r = 0; r < 4; r++)
      Tbuf[(size_t)blk * 4096 + (size_t)(d + r) * 64 + v] = tacc[v0][r];
  }
}

// ---------------- pass C: parallel chunk-state scan; S_in emitted bf16 ----------------
__global__ __launch_bounds__(256) void gla_state_scan2(const float* __restrict__ Tbuf,
                                                       const float* __restrict__ Dbuf,
                                                       float* __restrict__ Sfin,
                                                       u16* __restrict__ Sinb){
  int bh = blockIdx.x >> 4, seg = blockIdx.x & 15;
  int dv = seg * 256 + threadIdx.x;
  int d = dv >> 6;
  float S = 0.f;
  for (int c = 0; c < NC; c++){
    size_t slot = (size_t)bh * NC + c;
    float t  = Tbuf[slot * 4096 + dv];
    float dec = Dbuf[slot * 64 + d];
    Sinb[slot * 4096 + dv] = f2bf(S);
    S = dec * S + t;
  }
  Sfin[(size_t)bh * 4096 + dv] = S;
}

// ---------------- pass D (MFMA): outputs + RMSNorm + swish gate ----------------
__global__ __launch_bounds__(256) void gla_chunk_out2(const u16* __restrict__ Qb,
                                                      const u16* __restrict__ Kb,
                                                      const u16* __restrict__ Vb,
                                                      const u16* __restrict__ CG,
                                                      const u16* __restrict__ Sinb,
                                                      const u16* __restrict__ Gb,
                                                      const float* __restrict__ gnw,
                                                      u16* __restrict__ OG){
  __shared__ u16 QT[64 * 72];   // q~ rows t, k=d
  __shared__ u16 KT[64 * 72];   // k~ rows j, k=d ; reused for gate after matmul1
  __shared__ u16 VT[64 * 72];   // V^T rows v, k=t
  __shared__ u16 ST[64 * 72];   // S_in^T rows v, k=d ; reused for output staging
  __shared__ u16 PS[64 * 72];   // masked P rows t, k=j
  int blk = blockIdx.x;
  int c = blk & (NC - 1), bh = blk >> 5;
  int b = bh >> 4, h = bh & 15;
  int tid = threadIdx.x;
  int lane = tid & 63, w = tid >> 6;
  int lr = lane & 15, lk = lane >> 4;
  int tr = tid >> 2, tc = (tid & 3) * 16;
  size_t gbase = ((size_t)(b * L_SEQ + c * 64)) * HID + h * 64;

  // ---- stage q~, k~, V^T, S^T ----
  {
    float cg[16];
    const u16* cgp = CG + gbase + (size_t)tr * HID + tc;
    uint4 a0 = *(const uint4*)cgp, a1 = *(const uint4*)(cgp + 8);
    const u16* au = (const u16*)&a0; const u16* au2 = (const u16*)&a1;
    #pragma unroll
    for (int e = 0; e < 8; e++){ cg[e] = bf2f(au[e]); cg[8 + e] = bf2f(au2[e]); }
    const u16* qp = Qb + gbase + (size_t)tr * HID + tc;
    const u16* kp = Kb + gbase + (size_t)tr * HID + tc;
    const u16* vp = Vb + gbase + (size_t)tr * HID + tc;
    uint4 qr0 = *(const uint4*)qp, qr1 = *(const uint4*)(qp + 8);
    uint4 kr0 = *(const uint4*)kp, kr1 = *(const uint4*)(kp + 8);
    uint4 vr0 = *(const uint4*)vp, vr1 = *(const uint4*)(vp + 8);
    const u16* qu = (const u16*)&qr0; const u16* qu2 = (const u16*)&qr1;
    const u16* ku = (const u16*)&kr0; const u16* ku2 = (const u16*)&kr1;
    const u16* vu = (const u16*)&vr0; const u16* vu2 = (const u16*)&vr1;
    u16 qt[16] __attribute__((aligned(16)));
    u16 kt[16] __attribute__((aligned(16)));
    #pragma unroll
    for (int e = 0; e < 8; e++){
      float ec0 = __expf(cg[e]),  ei0 = __expf(-cg[e]);
      float ec1 = __expf(cg[8+e]), ei1 = __expf(-cg[8+e]);
      qt[e]     = f2bf(bf2f(qu[e])  * ec0 * QSCALE);
      qt[8 + e] = f2bf(bf2f(qu2[e]) * ec1 * QSCALE);
      kt[e]     = f2bf(bf2f(ku[e])  * ei0);
      kt[8 + e] = f2bf(bf2f(ku2[e]) * ei1);
      VT[(tc + e) * 72 + tr]     = vu[e];
      VT[(tc + 8 + e) * 72 + tr] = vu2[e];
    }
    *(uint4*)&QT[tr * 72 + tc]     = *(uint4*)&qt[0];
    *(uint4*)&QT[tr * 72 + tc + 8] = *(uint4*)&qt[8];
    *(uint4*)&KT[tr * 72 + tc]     = *(uint4*)&kt[0];
    *(uint4*)&KT[tr * 72 + tc + 8] = *(uint4*)&kt[8];
    const u16* sp = Sinb + (size_t)blk * 4096 + (size_t)tr * 64 + tc;
    uint4 s0 = *(const uint4*)sp, s1 = *(const uint4*)(sp + 8);
    const u16* su = (const u16*)&s0; const u16* su2 = (const u16*)&s1;
    #pragma unroll
    for (int e = 0; e < 8; e++){
      ST[(tc + e) * 72 + tr]     = su[e];
      ST[(tc + 8 + e) * 72 + tr] = su2[e];
    }
  }
  __syncthreads();

  // ---- matmul 1: P = q~ @ k~^T, masked, -> PS (bf16) ----
  int R0 = w * 16;
  {
    f32x4 pacc[4];
    #pragma unroll
    for (int j = 0; j < 4; j++)
      #pragma unroll
      for (int e = 0; e < 4; e++) pacc[j][e] = 0.f;
    #pragma unroll
    for (int ks = 0; ks < 2; ks++){
      bf16x8 a = *(const bf16x8*)&QT[(R0 + lr) * 72 + ks * 32 + lk * 8];
      #pragma unroll
      for (int j0 = 0; j0 < 4; j0++){
        bf16x8 bb = *(const bf16x8*)&KT[(j0 * 16 + lr) * 72 + ks * 32 + lk * 8];
        pacc[j0] = __builtin_amdgcn_mfma_f32_16x16x32_bf16(a, bb, pacc[j0], 0, 0, 0);
      }
    }
    #pragma unroll
    for (int j0 = 0; j0 < 4; j0++){
      int j = j0 * 16 + lr;
      #pragma unroll
      for (int r = 0; r < 4; r++){
        int t = R0 + lk * 4 + r;
        PS[t * 72 + j] = (j <= t) ? f2bf(pacc[j0][r]) : (u16)0;
      }
    }
  }
  __syncthreads();

  // ---- stage gate into KT space; matmul 3 (q~ @ S^T) + matmul 2 (P @ V^T) ----
  uint4 gr0, gr1;
  {
    const u16* gp = Gb + gbase + (size_t)tr * HID + tc;
    gr0 = *(const uint4*)gp; gr1 = *(const uint4*)(gp + 8);
  }
  f32x4 oacc[4];
  #pragma unroll
  for (int v = 0; v < 4; v++)
    #pragma unroll
    for (int e = 0; e < 4; e++) oacc[v][e] = 0.f;
  #pragma unroll
  for (int ks = 0; ks < 2; ks++){
    bf16x8 a = *(const bf16x8*)&QT[(R0 + lr) * 72 + ks * 32 + lk * 8];
    #pragma unroll
    for (int v0 = 0; v0 < 4; v0++){
      bf16x8 bb = *(const bf16x8*)&ST[(v0 * 16 + lr) * 72 + ks * 32 + lk * 8];
      oacc[v0] = __builtin_amdgcn_mfma_f32_16x16x32_bf16(a, bb, oacc[v0], 0, 0, 0);
    }
  }
  #pragma unroll
  for (int ks = 0; ks < 2; ks++){
    bf16x8 a = *(const bf16x8*)&PS[(R0 + lr) * 72 + ks * 32 + lk * 8];
    #pragma unroll
    for (int v0 = 0; v0 < 4; v0++){
      bf16x8 bb = *(const bf16x8*)&VT[(v0 * 16 + lr) * 72 + ks * 32 + lk * 8];
      oacc[v0] = __builtin_amdgcn_mfma_f32_16x16x32_bf16(a, bb, oacc[v0], 0, 0, 0);
    }
  }
  *(uint4*)&KT[tr * 72 + tc]     = gr0;   // gate
  *(uint4*)&KT[tr * 72 + tc + 8] = gr1;
  __syncthreads();

  // ---- epilogue: RMSNorm over v, affine, swish gate; stage to ST then coalesced out ----
  {
    float gnv[4];
    #pragma unroll
    for (int v0 = 0; v0 < 4; v0++) gnv[v0] = gnw[v0 * 16 + lr];
    #pragma unroll
    for (int r = 0; r < 4; r++){
      float ssq = 0.f;
      #pragma unroll
      for (int v0 = 0; v0 < 4; v0++) ssq += oacc[v0][r] * oacc[v0][r];
      ssq += __shfl_xor(ssq, 1, 64);
      ssq += __shfl_xor(ssq, 2, 64);
      ssq += __shfl_xor(ssq, 4, 64);
      ssq += __shfl_xor(ssq, 8, 64);
      float rn = rsqrtf(ssq * (1.0f / 64.0f) + GEPS);
      int t = R0 + lk * 4 + r;
      #pragma unroll
      for (int v0 = 0; v0 < 4; v0++){
        float g = bf2f(KT[t * 72 + v0 * 16 + lr]);
        float sw = g / (1.f + __expf(-g));
        ST[t * 72 + v0 * 16 + lr] = f2bf(oacc[v0][r] * rn * gnv[v0] * sw);
      }
    }
  }
  __syncthreads();
  {
    uint4 o0 = *(uint4*)&ST[tr * 72 + tc];
    uint4 o1 = *(uint4*)&ST[tr * 72 + tc + 8];
    u16* op = OG + gbase + (size_t)tr * HID + tc;
    *(uint4*)op       = o0;
    *(uint4*)(op + 8) = o1;
  }
}

// ---------------- host launcher ----------------
extern "C" void kernel_launch(void* const* d_in, const int* in_sizes, int n_in,
                              void* d_out, int out_size, void* d_ws, size_t ws_size,
                              hipStream_t stream){
  (void)in_sizes; (void)n_in; (void)out_size;
  const float* x   = (const float*)d_in[0];
  const float* Wq  = (const float*)d_in[1];
  const float* Wk  = (const float*)d_in[2];
  const float* Wv  = (const float*)d_in[3];
  const float* Wg1 = (const float*)d_in[4];
  const float* Wg2 = (const float*)d_in[5];
  const float* bg2 = (const float*)d_in[6];
  const float* Wg  = (const float*)d_in[7];
  const float* gnw = (const float*)d_in[8];
  const float* Wo  = (const float*)d_in[9];
  float* out = (float*)d_out;

  char* ws = (char*)d_ws;
  size_t off = 0;
  auto alloc = [&](size_t bytes) -> char* {
    char* p = ws + off; off += (bytes + 255) & ~(size_t)255; return p;
  };
  u16* xb   = (u16*)alloc((size_t)MTOK * HID * 2);
  u16* WTq  = (u16*)alloc((size_t)HID * HID * 2);   // WTq..WTg contiguous: combined N=4096
  u16* WTk  = (u16*)alloc((size_t)HID * HID * 2);
  u16* WTv  = (u16*)alloc((size_t)HID * HID * 2);
  u16* WTg  = (u16*)alloc((size_t)HID * HID * 2);
  u16* WTo  = (u16*)alloc((size_t)HID * HID * 2);
  u16* Qb   = (u16*)alloc((size_t)MTOK * HID * 2);  // Qb..Gb contiguous: sel-strided C
  u16* Kb   = (u16*)alloc((size_t)MTOK * HID * 2);
  u16* Vb   = (u16*)alloc((size_t)MTOK * HID * 2);
  u16* Gb   = (u16*)alloc((size_t)MTOK * HID * 2);
  u16* CGb  = (u16*)alloc((size_t)MTOK * HID * 2);
  float* xg1b = (float*)alloc((size_t)MTOK * 16 * 4);
  float* Tbuf = (float*)alloc((size_t)1024 * 4096 * 4);
  float* Dbuf = (float*)alloc((size_t)1024 * 64 * 4);
  u16* Sinb = (u16*)alloc((size_t)1024 * 4096 * 2);
  u16* OG   = (u16*)alloc((size_t)MTOK * HID * 2);
  if (off > ws_size) return;
  // split-K partials alias dead Q/K/V/G region (2 * 16.8 MB = exactly Qb..Gb span)
  float* Pbuf = (float*)Qb;

  gla_xg1<<<1024, 256, 0, stream>>>(x, Wg1, xg1b, xb);
  dim3 tg(32, 32, 5);
  gla_transpose5<<<tg, 256, 0, stream>>>(Wq, Wk, Wv, Wg, Wo, WTq, WTk, WTv, WTg, WTo);
  gla_gkcg<<<256, 256, 0, stream>>>(xg1b, Wg2, bg2, CGb);

  dim3 gq(16, 32);
  gla_gemm_qkvg<<<gq, 512, 0, stream>>>(xb, WTq, Qb);   // Q,K,V,G in one dispatch

  gla_chunk_state2<<<1024, 256, 0, stream>>>(Kb, Vb, CGb, Tbuf, Dbuf);
  gla_state_scan2<<<512, 256, 0, stream>>>(Tbuf, Dbuf, out + (size_t)MTOK * HID, Sinb);
  gla_chunk_out2<<<1024, 256, 0, stream>>>(Qb, Kb, Vb, CGb, Sinb, Gb, gnw, OG);

  dim3 go(32, 8, 2);
  gla_gemm_ws<<<go, 256, 0, stream>>>(OG, WTo, Pbuf);
  gla_add2<<<4096, 256, 0, stream>>>(Pbuf, out);
}

// Round 6
// 140.318 us; speedup vs baseline: 1.1240x; 1.0708x over previous
//
#include <hip/hip_runtime.h>
#include <hip/hip_bf16.h>

typedef unsigned short u16;
typedef __attribute__((ext_vector_type(8))) short bf16x8;
typedef __attribute__((ext_vector_type(4))) float f32x4;

#define L_SEQ 2048
#define HID 1024
#define NC 32
#define MTOK 4096
#define GEPS 1e-5f
#define QSCALE 0.125f

__device__ __forceinline__ float bf2f(u16 u){ union{unsigned i; float f;}c; c.i=(unsigned)u<<16; return c.f; }
__device__ __forceinline__ u16 f2bf(float f){ union{__hip_bfloat16 h; u16 u;}c; c.h=__float2bfloat16(f); return c.u; }

// transposed-LDS swizzle: rows with q-spaced indices alias banks (q*16*72*2/4 % 32 == 0).
// XOR col bits 3..4 with row bits 4..5 -> 8-way write conflict becomes 2-way (free).
// col runs of 8 preserved (XOR is a multiple of 8).
__device__ __forceinline__ int swz72(int row, int col){ return row * 72 + (col ^ ((row >> 1) & 24)); }

__device__ __forceinline__ void gload_lds16(const u16* g, u16* l){
  __builtin_amdgcn_global_load_lds((const __attribute__((address_space(1))) void*)g,
                                   (__attribute__((address_space(3))) void*)l, 16, 0, 0);
}

// ---------------- 5x W (KxN f32) -> WT (NxK bf16), batched over z ----------------
__global__ __launch_bounds__(256) void gla_transpose5(const float* W0, const float* W1,
                                                      const float* W2, const float* W3,
                                                      const float* W4,
                                                      u16* D0, u16* D1, u16* D2, u16* D3, u16* D4){
  const float* W; u16* D;
  switch (blockIdx.z){
    case 0: W = W0; D = D0; break;
    case 1: W = W1; D = D1; break;
    case 2: W = W2; D = D2; break;
    case 3: W = W3; D = D3; break;
    default: W = W4; D = D4; break;
  }
  __shared__ float tile[32][33];
  int tx = threadIdx.x & 31, ty = threadIdx.x >> 5;
  int n0 = blockIdx.x * 32, k0 = blockIdx.y * 32;
  #pragma unroll
  for (int r = ty; r < 32; r += 8)
    tile[r][tx] = W[(size_t)(k0 + r) * HID + n0 + tx];
  __syncthreads();
  #pragma unroll
  for (int r = ty; r < 32; r += 8)
    D[(size_t)(n0 + r) * HID + k0 + tx] = f2bf(tile[tx][r]);
}

// ---------------- fused: xg1 = x @ Wg1 AND xb = bf16(x) ----------------
__global__ __launch_bounds__(256) void gla_xg1(const float* __restrict__ x,
                                               const float* __restrict__ Wg1,
                                               float* __restrict__ xg1,
                                               u16* __restrict__ xb){
  int lane = threadIdx.x & 63, wid = threadIdx.x >> 6;
  int row = blockIdx.x * 4 + wid;
  const float* xr = x + (size_t)row * HID;
  u16* xbr = xb + (size_t)row * HID;
  float acc[16];
  #pragma unroll
  for (int n = 0; n < 16; n++) acc[n] = 0.f;
  for (int k = lane; k < HID; k += 64){
    float xv = xr[k];
    xbr[k] = f2bf(xv);
    const float4* wr = (const float4*)(Wg1 + (size_t)k * 16);
    float4 w0 = wr[0], w1 = wr[1], w2 = wr[2], w3 = wr[3];
    acc[0]  += xv * w0.x; acc[1]  += xv * w0.y; acc[2]  += xv * w0.z; acc[3]  += xv * w0.w;
    acc[4]  += xv * w1.x; acc[5]  += xv * w1.y; acc[6]  += xv * w1.z; acc[7]  += xv * w1.w;
    acc[8]  += xv * w2.x; acc[9]  += xv * w2.y; acc[10] += xv * w2.z; acc[11] += xv * w2.w;
    acc[12] += xv * w3.x; acc[13] += xv * w3.y; acc[14] += xv * w3.z; acc[15] += xv * w3.w;
  }
  #pragma unroll
  for (int n = 0; n < 16; n++){
    #pragma unroll
    for (int off = 32; off > 0; off >>= 1)
      acc[n] += __shfl_down(acc[n], off, 64);
  }
  if (lane == 0){
    #pragma unroll
    for (int n = 0; n < 16; n++) xg1[(size_t)row * 16 + n] = acc[n];
  }
}

// ---------------- gate stage 2 + per-chunk cumsum: CG (bf16) ----------------
__global__ __launch_bounds__(256) void gla_gkcg(const float* __restrict__ xg1,
                                                const float* __restrict__ Wg2,
                                                const float* __restrict__ bg2,
                                                u16* __restrict__ CG){
  __shared__ float xs[64][16];
  int blk = blockIdx.x;
  int b = blk >> 7, r7 = blk & 127;
  int c = r7 >> 2, q = r7 & 3;
  int col = q * 256 + threadIdx.x;
  int tok0 = b * L_SEQ + c * 64;
  {
    int row = threadIdx.x >> 2, e4 = (threadIdx.x & 3) * 4;
    *(float4*)&xs[row][e4] = *(const float4*)&xg1[(size_t)(tok0 + row) * 16 + e4];
  }
  __syncthreads();
  float w[16];
  #pragma unroll
  for (int r = 0; r < 16; r++) w[r] = Wg2[r * HID + col];
  float bz = bg2[col];
  float cum = 0.f;
  for (int t = 0; t < 64; t++){
    float z = bz;
    #pragma unroll
    for (int r = 0; r < 16; r++) z += xs[t][r] * w[r];
    float ls = fminf(z, 0.f) - log1pf(__expf(-fabsf(z)));
    cum += ls * (1.0f / 16.0f);
    CG[(size_t)(tok0 + t) * HID + col] = f2bf(cum);
  }
}

// ---------------- QKVG GEMM: 256x128 tile, 512 thr / 8 waves, dbuf + counted vmcnt ------
__global__ __launch_bounds__(512) void gla_gemm_qkvg(const u16* __restrict__ A,
                                                     const u16* __restrict__ Bt,
                                                     u16* __restrict__ C){
  constexpr int NT = HID / 32;
  __shared__ u16 As[2][256 * 32];
  __shared__ u16 Bs[2][128 * 32];
  const int tid = threadIdx.x;
  const int lane = tid & 63, wid = tid >> 6;
  const int wm = wid >> 1, wn = wid & 1;
  const int lr = lane & 15, lk = lane >> 4;
  // T1 XCD-aware remap: 512 blocks, 8 XCDs, 64 blocks/XCD contiguous in (bn-major) space
  const int id = blockIdx.x + 16 * blockIdx.y;
  const int nid = (id & 7) * 64 + (id >> 3);
  const int bm = nid & 15, bn = nid >> 4;
  const int srow = tid >> 2;
  const int skw  = ((tid & 3) * 8) ^ ((srow & 3) << 3);
  const u16* Ag = A  + ((size_t)bm * 256 + srow) * HID + skw;
  const u16* Bg = Bt + ((size_t)bn * 128 + srow) * HID + skw;

  f32x4 acc[4][4];
  #pragma unroll
  for (int i = 0; i < 4; i++)
    #pragma unroll
    for (int j = 0; j < 4; j++)
      #pragma unroll
      for (int e = 0; e < 4; e++) acc[i][j][e] = 0.f;

  auto STAGE = [&](int buf, int kt){
    gload_lds16(Ag + kt * 32,                         &As[buf][tid * 8]);
    gload_lds16(Ag + (size_t)128 * HID + kt * 32,     &As[buf][4096 + tid * 8]);
    gload_lds16(Bg + kt * 32,                         &Bs[buf][tid * 8]);
  };

  STAGE(0, 0);
  for (int t = 0; t < NT; ++t){
    const int buf = t & 1;
    if (t + 1 < NT){
      STAGE(buf ^ 1, t + 1);
      asm volatile("s_waitcnt vmcnt(3)\ns_barrier" ::: "memory");
    } else {
      asm volatile("s_waitcnt vmcnt(0)\ns_barrier" ::: "memory");
    }
    bf16x8 af[4], bfr[4];
    #pragma unroll
    for (int m = 0; m < 4; m++){
      int row = wm * 64 + m * 16 + lr;
      af[m] = *(const bf16x8*)&As[buf][(row * 32 + lk * 8) ^ ((row & 3) << 3)];
    }
    #pragma unroll
    for (int n = 0; n < 4; n++){
      int row = wn * 64 + n * 16 + lr;
      bfr[n] = *(const bf16x8*)&Bs[buf][(row * 32 + lk * 8) ^ ((row & 3) << 3)];
    }
    __builtin_amdgcn_s_setprio(1);
    #pragma unroll
    for (int m = 0; m < 4; m++)
      #pragma unroll
      for (int n = 0; n < 4; n++)
        acc[m][n] = __builtin_amdgcn_mfma_f32_16x16x32_bf16(af[m], bfr[n], acc[m][n], 0, 0, 0);
    __builtin_amdgcn_s_setprio(0);
    __builtin_amdgcn_sched_barrier(0);
    asm volatile("s_barrier" ::: "memory");
  }

  #pragma unroll
  for (int i = 0; i < 4; i++)
    #pragma unroll
    for (int j = 0; j < 4; j++){
      int row0 = bm * 256 + wm * 64 + i * 16 + lk * 4;
      int cb   = bn * 128 + wn * 64 + j * 16 + lr;
      int sel  = cb >> 10, col = cb & 1023;
      size_t base = (size_t)sel * ((size_t)MTOK * HID) + (size_t)row0 * HID + col;
      #pragma unroll
      for (int r = 0; r < 4; r++)
        C[base + (size_t)r * HID] = f2bf(acc[i][j][r]);
    }
}

// ---------------- out GEMM: in-block split-K=2, 128x128 tile, 512 thr ----------------
// waves 0-3: K[0:512], waves 4-7: K[512:1024]; LDS f32 reduce (aliased onto staging).
__global__ __launch_bounds__(512) void gla_gemm_out_sk(const u16* __restrict__ A,
                                                       const u16* __restrict__ Bt,
                                                       float* __restrict__ C){
  constexpr int NT = 16;                  // 512 / 32 per K-group
  __shared__ __align__(16) char smem[128 * 132 * 4];   // 67584 B: staging (64KB) then f32 red
  u16* stage = (u16*)smem;
  float* red = (float*)smem;
  const int tid = threadIdx.x;
  const int lane = tid & 63, wid = tid >> 6;
  const int kg = wid >> 2;                // K-group 0/1
  const int wq = wid & 3;
  const int wm = wq >> 1, wn = wq & 1;
  const int lr = lane & 15, lk = lane >> 4;
  // T1 remap: 256 blocks; each XCD owns one bn column-panel
  const int id = blockIdx.x + 32 * blockIdx.y;
  const int nid = (id & 7) * 32 + (id >> 3);
  const int bm = nid & 31, bn = nid >> 5;
  const int srow = tid >> 2;
  const int skw  = ((tid & 3) * 8) ^ ((srow & 3) << 3);
  const u16* Ag0 = A  + ((size_t)bm * 128 + srow) * HID + skw;
  const u16* Bg0 = Bt + ((size_t)bn * 128 + srow) * HID + skw;
  const u16* Ag1 = Ag0 + 512;
  const u16* Bg1 = Bg0 + 512;

  f32x4 acc[4][4];
  #pragma unroll
  for (int i = 0; i < 4; i++)
    #pragma unroll
    for (int j = 0; j < 4; j++)
      #pragma unroll
      for (int e = 0; e < 4; e++) acc[i][j][e] = 0.f;

  auto STAGE = [&](int buf, int kt){
    gload_lds16(Ag0 + kt * 32, stage + (buf * 4 + 0) * 4096 + tid * 8);
    gload_lds16(Bg0 + kt * 32, stage + (buf * 4 + 1) * 4096 + tid * 8);
    gload_lds16(Ag1 + kt * 32, stage + (buf * 4 + 2) * 4096 + tid * 8);
    gload_lds16(Bg1 + kt * 32, stage + (buf * 4 + 3) * 4096 + tid * 8);
  };

  STAGE(0, 0);
  for (int t = 0; t < NT; ++t){
    const int buf = t & 1;
    if (t + 1 < NT){
      STAGE(buf ^ 1, t + 1);
      asm volatile("s_waitcnt vmcnt(4)\ns_barrier" ::: "memory");
    } else {
      asm volatile("s_waitcnt vmcnt(0)\ns_barrier" ::: "memory");
    }
    const u16* Ab = stage + (buf * 4 + kg * 2 + 0) * 4096;
    const u16* Bb = stage + (buf * 4 + kg * 2 + 1) * 4096;
    bf16x8 af[4], bfr[4];
    #pragma unroll
    for (int m = 0; m < 4; m++){
      int row = wm * 64 + m * 16 + lr;
      af[m] = *(const bf16x8*)&Ab[(row * 32 + lk * 8) ^ ((row & 3) << 3)];
    }
    #pragma unroll
    for (int n = 0; n < 4; n++){
      int row = wn * 64 + n * 16 + lr;
      bfr[n] = *(const bf16x8*)&Bb[(row * 32 + lk * 8) ^ ((row & 3) << 3)];
    }
    __builtin_amdgcn_s_setprio(1);
    #pragma unroll
    for (int m = 0; m < 4; m++)
      #pragma unroll
      for (int n = 0; n < 4; n++)
        acc[m][n] = __builtin_amdgcn_mfma_f32_16x16x32_bf16(af[m], bfr[n], acc[m][n], 0, 0, 0);
    __builtin_amdgcn_s_setprio(0);
    __builtin_amdgcn_sched_barrier(0);
    asm volatile("s_barrier" ::: "memory");
  }

  // reduce: kg1 dumps to LDS (stride 132 -> conflict-free), kg0 adds + stores
  if (kg == 1){
    #pragma unroll
    for (int i = 0; i < 4; i++)
      #pragma unroll
      for (int j = 0; j < 4; j++){
        int row = wm * 64 + i * 16 + lk * 4;
        int col = wn * 64 + j * 16 + lr;
        #pragma unroll
        for (int r = 0; r < 4; r++)
          red[(row + r) * 132 + col] = acc[i][j][r];
      }
  }
  __syncthreads();
  if (kg == 0){
    #pragma unroll
    for (int i = 0; i < 4; i++)
      #pragma unroll
      for (int j = 0; j < 4; j++){
        int row = wm * 64 + i * 16 + lk * 4;
        int col = wn * 64 + j * 16 + lr;
        #pragma unroll
        for (int r = 0; r < 4; r++)
          C[(size_t)(bm * 128 + row + r) * HID + bn * 128 + col] =
              acc[i][j][r] + red[(row + r) * 132 + col];
      }
  }
}

// ---------------- pass B (MFMA): T_c = K^hat^T @ V (bf16 out), D_c = exp(cg_last) -------
__global__ __launch_bounds__(256) void gla_chunk_state2(const u16* __restrict__ Kb,
                                                        const u16* __restrict__ Vb,
                                                        const u16* __restrict__ CG,
                                                        u16* __restrict__ Tbuf,
                                                        float* __restrict__ Dbuf){
  __shared__ u16 KHT[64 * 72];   // K^hat^T rows d, cols t (swizzled)
  __shared__ u16 VT[64 * 72];    // V^T rows v, cols t (swizzled)
  int blk = blockIdx.x;
  int c = blk & (NC - 1), bh = blk >> 5;
  int b = bh >> 4, h = bh & 15;
  int tid = threadIdx.x;
  int lane = tid & 63, w = tid >> 6;
  int lr = lane & 15, lk = lane >> 4;
  int tr = tid >> 2, tc = (tid & 3) * 16;
  size_t gbase = ((size_t)(b * L_SEQ + c * 64)) * HID + h * 64;

  float cg[16], cgl[16];
  {
    const u16* cgp = CG + gbase + (size_t)tr * HID + tc;
    const u16* clp = CG + gbase + (size_t)63 * HID + tc;
    uint4 a0 = *(const uint4*)cgp, a1 = *(const uint4*)(cgp + 8);
    uint4 l0 = *(const uint4*)clp, l1 = *(const uint4*)(clp + 8);
    const u16* au = (const u16*)&a0; const u16* au2 = (const u16*)&a1;
    const u16* lu = (const u16*)&l0; const u16* lu2 = (const u16*)&l1;
    #pragma unroll
    for (int e = 0; e < 8; e++){
      cg[e] = bf2f(au[e]); cg[8 + e] = bf2f(au2[e]);
      cgl[e] = bf2f(lu[e]); cgl[8 + e] = bf2f(lu2[e]);
    }
  }
  {
    const u16* kp = Kb + gbase + (size_t)tr * HID + tc;
    const u16* vp = Vb + gbase + (size_t)tr * HID + tc;
    uint4 kr0 = *(const uint4*)kp, kr1 = *(const uint4*)(kp + 8);
    uint4 vr0 = *(const uint4*)vp, vr1 = *(const uint4*)(vp + 8);
    const u16* ku = (const u16*)&kr0; const u16* ku2 = (const u16*)&kr1;
    const u16* vu = (const u16*)&vr0; const u16* vu2 = (const u16*)&vr1;
    #pragma unroll
    for (int e = 0; e < 8; e++){
      KHT[swz72(tc + e, tr)]     = f2bf(bf2f(ku[e])  * __expf(cgl[e]     - cg[e]));
      KHT[swz72(tc + 8 + e, tr)] = f2bf(bf2f(ku2[e]) * __expf(cgl[8 + e] - cg[8 + e]));
      VT[swz72(tc + e, tr)]      = vu[e];
      VT[swz72(tc + 8 + e, tr)]  = vu2[e];
    }
  }
  if (tr == 0){
    #pragma unroll
    for (int e = 0; e < 16; e++)
      Dbuf[(size_t)blk * 64 + tc + e] = __expf(cgl[e]);
  }
  __syncthreads();
  int R0 = w * 16;
  f32x4 tacc[4];
  #pragma unroll
  for (int v = 0; v < 4; v++)
    #pragma unroll
    for (int e = 0; e < 4; e++) tacc[v][e] = 0.f;
  #pragma unroll
  for (int ks = 0; ks < 2; ks++){
    bf16x8 a = *(const bf16x8*)&KHT[swz72(R0 + lr, ks * 32 + lk * 8)];
    #pragma unroll
    for (int v0 = 0; v0 < 4; v0++){
      bf16x8 bb = *(const bf16x8*)&VT[swz72(v0 * 16 + lr, ks * 32 + lk * 8)];
      tacc[v0] = __builtin_amdgcn_mfma_f32_16x16x32_bf16(a, bb, tacc[v0], 0, 0, 0);
    }
  }
  u16* Tp = Tbuf + (size_t)blk * 4096;
  #pragma unroll
  for (int v0 = 0; v0 < 4; v0++){
    int d = R0 + lk * 4, v = v0 * 16 + lr;
    #pragma unroll
    for (int r = 0; r < 4; r++)
      Tp[(d + r) * 64 + v] = f2bf(tacc[v0][r]);
  }
}

// ---------------- pass C: parallel chunk-state scan (bf16 T in, bf16 S_in out) ----------
__global__ __launch_bounds__(256) void gla_state_scan2(const u16* __restrict__ Tbuf,
                                                       const float* __restrict__ Dbuf,
                                                       float* __restrict__ Sfin,
                                                       u16* __restrict__ Sinb){
  int bh = blockIdx.x >> 4, seg = blockIdx.x & 15;
  int dv = seg * 256 + threadIdx.x;
  int d = dv >> 6;
  float S = 0.f;
  for (int c = 0; c < NC; c++){
    size_t slot = (size_t)bh * NC + c;
    float t  = bf2f(Tbuf[slot * 4096 + dv]);
    float dec = Dbuf[slot * 64 + d];
    Sinb[slot * 4096 + dv] = f2bf(S);
    S = dec * S + t;
  }
  Sfin[(size_t)bh * 4096 + dv] = S;
}

// ---------------- pass D (MFMA): outputs + RMSNorm + swish gate ----------------
__global__ __launch_bounds__(256) void gla_chunk_out2(const u16* __restrict__ Qb,
                                                      const u16* __restrict__ Kb,
                                                      const u16* __restrict__ Vb,
                                                      const u16* __restrict__ CG,
                                                      const u16* __restrict__ Sinb,
                                                      const u16* __restrict__ Gb,
                                                      const float* __restrict__ gnw,
                                                      u16* __restrict__ OG){
  __shared__ u16 QT[64 * 72];   // q~ rows t, cols d (natural, vector writes)
  __shared__ u16 KT[64 * 72];   // k~ rows j, cols d ; reused for gate after matmul1
  __shared__ u16 VT[64 * 72];   // V^T rows v, cols t (swizzled)
  __shared__ u16 ST[64 * 72];   // S^T rows v, cols d (swizzled); reused for out staging
  __shared__ u16 PS[64 * 72];   // masked P rows t, cols j
  int blk = blockIdx.x;
  int c = blk & (NC - 1), bh = blk >> 5;
  int b = bh >> 4, h = bh & 15;
  int tid = threadIdx.x;
  int lane = tid & 63, w = tid >> 6;
  int lr = lane & 15, lk = lane >> 4;
  int tr = tid >> 2, tc = (tid & 3) * 16;
  size_t gbase = ((size_t)(b * L_SEQ + c * 64)) * HID + h * 64;

  // ---- stage q~, k~, V^T, S^T ----
  {
    float cg[16];
    const u16* cgp = CG + gbase + (size_t)tr * HID + tc;
    uint4 a0 = *(const uint4*)cgp, a1 = *(const uint4*)(cgp + 8);
    const u16* au = (const u16*)&a0; const u16* au2 = (const u16*)&a1;
    #pragma unroll
    for (int e = 0; e < 8; e++){ cg[e] = bf2f(au[e]); cg[8 + e] = bf2f(au2[e]); }
    const u16* qp = Qb + gbase + (size_t)tr * HID + tc;
    const u16* kp = Kb + gbase + (size_t)tr * HID + tc;
    const u16* vp = Vb + gbase + (size_t)tr * HID + tc;
    uint4 qr0 = *(const uint4*)qp, qr1 = *(const uint4*)(qp + 8);
    uint4 kr0 = *(const uint4*)kp, kr1 = *(const uint4*)(kp + 8);
    uint4 vr0 = *(const uint4*)vp, vr1 = *(const uint4*)(vp + 8);
    const u16* qu = (const u16*)&qr0; const u16* qu2 = (const u16*)&qr1;
    const u16* ku = (const u16*)&kr0; const u16* ku2 = (const u16*)&kr1;
    const u16* vu = (const u16*)&vr0; const u16* vu2 = (const u16*)&vr1;
    u16 qt[16] __attribute__((aligned(16)));
    u16 kt[16] __attribute__((aligned(16)));
    #pragma unroll
    for (int e = 0; e < 8; e++){
      float ec0 = __expf(cg[e]),  ei0 = __expf(-cg[e]);
      float ec1 = __expf(cg[8+e]), ei1 = __expf(-cg[8+e]);
      qt[e]     = f2bf(bf2f(qu[e])  * ec0 * QSCALE);
      qt[8 + e] = f2bf(bf2f(qu2[e]) * ec1 * QSCALE);
      kt[e]     = f2bf(bf2f(ku[e])  * ei0);
      kt[8 + e] = f2bf(bf2f(ku2[e]) * ei1);
      VT[swz72(tc + e, tr)]     = vu[e];
      VT[swz72(tc + 8 + e, tr)] = vu2[e];
    }
    *(uint4*)&QT[tr * 72 + tc]     = *(uint4*)&qt[0];
    *(uint4*)&QT[tr * 72 + tc + 8] = *(uint4*)&qt[8];
    *(uint4*)&KT[tr * 72 + tc]     = *(uint4*)&kt[0];
    *(uint4*)&KT[tr * 72 + tc + 8] = *(uint4*)&kt[8];
    const u16* sp = Sinb + (size_t)blk * 4096 + (size_t)tr * 64 + tc;
    uint4 s0 = *(const uint4*)sp, s1 = *(const uint4*)(sp + 8);
    const u16* su = (const u16*)&s0; const u16* su2 = (const u16*)&s1;
    #pragma unroll
    for (int e = 0; e < 8; e++){
      ST[swz72(tc + e, tr)]     = su[e];
      ST[swz72(tc + 8 + e, tr)] = su2[e];
    }
  }
  __syncthreads();

  // ---- matmul 1: P = q~ @ k~^T, masked, -> PS (bf16) ----
  int R0 = w * 16;
  {
    f32x4 pacc[4];
    #pragma unroll
    for (int j = 0; j < 4; j++)
      #pragma unroll
      for (int e = 0; e < 4; e++) pacc[j][e] = 0.f;
    #pragma unroll
    for (int ks = 0; ks < 2; ks++){
      bf16x8 a = *(const bf16x8*)&QT[(R0 + lr) * 72 + ks * 32 + lk * 8];
      #pragma unroll
      for (int j0 = 0; j0 < 4; j0++){
        bf16x8 bb = *(const bf16x8*)&KT[(j0 * 16 + lr) * 72 + ks * 32 + lk * 8];
        pacc[j0] = __builtin_amdgcn_mfma_f32_16x16x32_bf16(a, bb, pacc[j0], 0, 0, 0);
      }
    }
    #pragma unroll
    for (int j0 = 0; j0 < 4; j0++){
      int j = j0 * 16 + lr;
      #pragma unroll
      for (int r = 0; r < 4; r++){
        int t = R0 + lk * 4 + r;
        PS[t * 72 + j] = (j <= t) ? f2bf(pacc[j0][r]) : (u16)0;
      }
    }
  }
  __syncthreads();

  // ---- stage gate into KT space; matmul 3 (q~ @ S^T) + matmul 2 (P @ V^T) ----
  uint4 gr0, gr1;
  {
    const u16* gp = Gb + gbase + (size_t)tr * HID + tc;
    gr0 = *(const uint4*)gp; gr1 = *(const uint4*)(gp + 8);
  }
  f32x4 oacc[4];
  #pragma unroll
  for (int v = 0; v < 4; v++)
    #pragma unroll
    for (int e = 0; e < 4; e++) oacc[v][e] = 0.f;
  #pragma unroll
  for (int ks = 0; ks < 2; ks++){
    bf16x8 a = *(const bf16x8*)&QT[(R0 + lr) * 72 + ks * 32 + lk * 8];
    #pragma unroll
    for (int v0 = 0; v0 < 4; v0++){
      bf16x8 bb = *(const bf16x8*)&ST[swz72(v0 * 16 + lr, ks * 32 + lk * 8)];
      oacc[v0] = __builtin_amdgcn_mfma_f32_16x16x32_bf16(a, bb, oacc[v0], 0, 0, 0);
    }
  }
  #pragma unroll
  for (int ks = 0; ks < 2; ks++){
    bf16x8 a = *(const bf16x8*)&PS[(R0 + lr) * 72 + ks * 32 + lk * 8];
    #pragma unroll
    for (int v0 = 0; v0 < 4; v0++){
      bf16x8 bb = *(const bf16x8*)&VT[swz72(v0 * 16 + lr, ks * 32 + lk * 8)];
      oacc[v0] = __builtin_amdgcn_mfma_f32_16x16x32_bf16(a, bb, oacc[v0], 0, 0, 0);
    }
  }
  *(uint4*)&KT[tr * 72 + tc]     = gr0;   // gate
  *(uint4*)&KT[tr * 72 + tc + 8] = gr1;
  __syncthreads();

  // ---- epilogue: RMSNorm over v, affine, swish gate; stage to ST then coalesced out ----
  {
    float gnv[4];
    #pragma unroll
    for (int v0 = 0; v0 < 4; v0++) gnv[v0] = gnw[v0 * 16 + lr];
    #pragma unroll
    for (int r = 0; r < 4; r++){
      float ssq = 0.f;
      #pragma unroll
      for (int v0 = 0; v0 < 4; v0++) ssq += oacc[v0][r] * oacc[v0][r];
      ssq += __shfl_xor(ssq, 1, 64);
      ssq += __shfl_xor(ssq, 2, 64);
      ssq += __shfl_xor(ssq, 4, 64);
      ssq += __shfl_xor(ssq, 8, 64);
      float rn = rsqrtf(ssq * (1.0f / 64.0f) + GEPS);
      int t = R0 + lk * 4 + r;
      #pragma unroll
      for (int v0 = 0; v0 < 4; v0++){
        float g = bf2f(KT[t * 72 + v0 * 16 + lr]);
        float sw = g / (1.f + __expf(-g));
        ST[swz72(t, v0 * 16 + lr)] = f2bf(oacc[v0][r] * rn * gnv[v0] * sw);
      }
    }
  }
  __syncthreads();
  {
    uint4 o0 = *(uint4*)&ST[swz72(tr, tc)];
    uint4 o1 = *(uint4*)&ST[swz72(tr, tc + 8)];
    u16* op = OG + gbase + (size_t)tr * HID + tc;
    *(uint4*)op       = o0;
    *(uint4*)(op + 8) = o1;
  }
}

// ---------------- host launcher ----------------
extern "C" void kernel_launch(void* const* d_in, const int* in_sizes, int n_in,
                              void* d_out, int out_size, void* d_ws, size_t ws_size,
                              hipStream_t stream){
  (void)in_sizes; (void)n_in; (void)out_size;
  const float* x   = (const float*)d_in[0];
  const float* Wq  = (const float*)d_in[1];
  const float* Wk  = (const float*)d_in[2];
  const float* Wv  = (const float*)d_in[3];
  const float* Wg1 = (const float*)d_in[4];
  const float* Wg2 = (const float*)d_in[5];
  const float* bg2 = (const float*)d_in[6];
  const float* Wg  = (const float*)d_in[7];
  const float* gnw = (const float*)d_in[8];
  const float* Wo  = (const float*)d_in[9];
  float* out = (float*)d_out;

  char* ws = (char*)d_ws;
  size_t off = 0;
  auto alloc = [&](size_t bytes) -> char* {
    char* p = ws + off; off += (bytes + 255) & ~(size_t)255; return p;
  };
  u16* xb   = (u16*)alloc((size_t)MTOK * HID * 2);
  u16* WTq  = (u16*)alloc((size_t)HID * HID * 2);   // WTq..WTg contiguous: combined N=4096
  u16* WTk  = (u16*)alloc((size_t)HID * HID * 2);
  u16* WTv  = (u16*)alloc((size_t)HID * HID * 2);
  u16* WTg  = (u16*)alloc((size_t)HID * HID * 2);
  u16* WTo  = (u16*)alloc((size_t)HID * HID * 2);
  u16* Qb   = (u16*)alloc((size_t)MTOK * HID * 2);  // Qb..Gb contiguous: sel-strided C
  u16* Kb   = (u16*)alloc((size_t)MTOK * HID * 2);
  u16* Vb   = (u16*)alloc((size_t)MTOK * HID * 2);
  u16* Gb   = (u16*)alloc((size_t)MTOK * HID * 2);
  u16* CGb  = (u16*)alloc((size_t)MTOK * HID * 2);
  float* xg1b = (float*)alloc((size_t)MTOK * 16 * 4);
  u16* Tbuf = (u16*)alloc((size_t)1024 * 4096 * 2);
  float* Dbuf = (float*)alloc((size_t)1024 * 64 * 4);
  u16* Sinb = (u16*)alloc((size_t)1024 * 4096 * 2);
  u16* OG   = (u16*)alloc((size_t)MTOK * HID * 2);
  if (off > ws_size) return;

  gla_xg1<<<1024, 256, 0, stream>>>(x, Wg1, xg1b, xb);
  dim3 tg(32, 32, 5);
  gla_transpose5<<<tg, 256, 0, stream>>>(Wq, Wk, Wv, Wg, Wo, WTq, WTk, WTv, WTg, WTo);
  gla_gkcg<<<256, 256, 0, stream>>>(xg1b, Wg2, bg2, CGb);

  dim3 gq(16, 32);
  gla_gemm_qkvg<<<gq, 512, 0, stream>>>(xb, WTq, Qb);   // Q,K,V,G in one dispatch

  gla_chunk_state2<<<1024, 256, 0, stream>>>(Kb, Vb, CGb, Tbuf, Dbuf);
  gla_state_scan2<<<512, 256, 0, stream>>>(Tbuf, Dbuf, out + (size_t)MTOK * HID, Sinb);
  gla_chunk_out2<<<1024, 256, 0, stream>>>(Qb, Kb, Vb, CGb, Sinb, Gb, gnw, OG);

  dim3 go(32, 8);
  gla_gemm_out_sk<<<go, 512, 0, stream>>>(OG, WTo, out);
}

// Round 7
// 135.840 us; speedup vs baseline: 1.1611x; 1.0330x over previous
//
#include <hip/hip_runtime.h>
#include <hip/hip_bf16.h>

typedef unsigned short u16;
typedef __attribute__((ext_vector_type(8))) short bf16x8;
typedef __attribute__((ext_vector_type(4))) float f32x4;

#define L_SEQ 2048
#define HID 1024
#define NC 32
#define MTOK 4096
#define GEPS 1e-5f
#define QSCALE 0.125f

__device__ __forceinline__ float bf2f(u16 u){ union{unsigned i; float f;}c; c.i=(unsigned)u<<16; return c.f; }
__device__ __forceinline__ u16 f2bf(float f){ union{__hip_bfloat16 h; u16 u;}c; c.h=__float2bfloat16(f); return c.u; }

// transposed-LDS swizzle (rows 16 apart alias banks): XOR col bits 3..4 with row bits 4..5.
__device__ __forceinline__ int swz72(int row, int col){ return row * 72 + (col ^ ((row >> 1) & 24)); }
// C-fragment-shaped scatter swizzle: rows t = base+4*lk+r -> XOR by 8*lk spreads banks.
__device__ __forceinline__ int swzc(int t){ return ((t >> 2) & 3) << 3; }

__device__ __forceinline__ void gload_lds16(const u16* g, u16* l){
  __builtin_amdgcn_global_load_lds((const __attribute__((address_space(1))) void*)g,
                                   (__attribute__((address_space(3))) void*)l, 16, 0, 0);
}

// ---------------- fused prep: xg1 = x @ Wg1, xb = bf16(x), 5 weight transposes ----------
__global__ __launch_bounds__(256) void gla_prep(const float* __restrict__ x,
                                                const float* __restrict__ Wg1,
                                                float* __restrict__ xg1,
                                                u16* __restrict__ xb,
                                                const float* W0, const float* W1,
                                                const float* W2, const float* W3,
                                                const float* W4,
                                                u16* D0, u16* D1, u16* D2, u16* D3, u16* D4){
  __shared__ float tile[32][33];
  int bid = blockIdx.x;
  if (bid < 1024){
    int lane = threadIdx.x & 63, wid = threadIdx.x >> 6;
    int row = bid * 4 + wid;
    const float* xr = x + (size_t)row * HID;
    u16* xbr = xb + (size_t)row * HID;
    float acc[16];
    #pragma unroll
    for (int n = 0; n < 16; n++) acc[n] = 0.f;
    #pragma unroll
    for (int i = 0; i < 4; i++){
      int k = i * 256 + lane * 4;
      float4 x4 = *(const float4*)&xr[k];
      u16 xo[4] __attribute__((aligned(8))) = { f2bf(x4.x), f2bf(x4.y), f2bf(x4.z), f2bf(x4.w) };
      *(uint2*)&xbr[k] = *(uint2*)xo;
      const float xv4[4] = { x4.x, x4.y, x4.z, x4.w };
      #pragma unroll
      for (int e = 0; e < 4; e++){
        float xv = xv4[e];
        const float4* wr = (const float4*)(Wg1 + (size_t)(k + e) * 16);
        float4 w0 = wr[0], w1 = wr[1], w2 = wr[2], w3 = wr[3];
        acc[0]  += xv * w0.x; acc[1]  += xv * w0.y; acc[2]  += xv * w0.z; acc[3]  += xv * w0.w;
        acc[4]  += xv * w1.x; acc[5]  += xv * w1.y; acc[6]  += xv * w1.z; acc[7]  += xv * w1.w;
        acc[8]  += xv * w2.x; acc[9]  += xv * w2.y; acc[10] += xv * w2.z; acc[11] += xv * w2.w;
        acc[12] += xv * w3.x; acc[13] += xv * w3.y; acc[14] += xv * w3.z; acc[15] += xv * w3.w;
      }
    }
    #pragma unroll
    for (int n = 0; n < 16; n++){
      #pragma unroll
      for (int off = 32; off > 0; off >>= 1)
        acc[n] += __shfl_down(acc[n], off, 64);
    }
    if (lane == 0){
      #pragma unroll
      for (int n = 0; n < 16; n++) xg1[(size_t)row * 16 + n] = acc[n];
    }
  } else {
    int id = bid - 1024;
    int z = id >> 10, rem = id & 1023;
    int bx = rem & 31, by = rem >> 5;
    const float* W; u16* D;
    switch (z){
      case 0: W = W0; D = D0; break;
      case 1: W = W1; D = D1; break;
      case 2: W = W2; D = D2; break;
      case 3: W = W3; D = D3; break;
      default: W = W4; D = D4; break;
    }
    int tx = threadIdx.x & 31, ty = threadIdx.x >> 5;
    int n0 = bx * 32, k0 = by * 32;
    #pragma unroll
    for (int r = ty; r < 32; r += 8)
      tile[r][tx] = W[(size_t)(k0 + r) * HID + n0 + tx];
    __syncthreads();
    #pragma unroll
    for (int r = ty; r < 32; r += 8)
      D[(size_t)(n0 + r) * HID + k0 + tx] = f2bf(tile[tx][r]);
  }
}

// ---------------- gate stage 2 + per-chunk cumsum: CG (bf16) ----------------
__global__ __launch_bounds__(256) void gla_gkcg(const float* __restrict__ xg1,
                                                const float* __restrict__ Wg2,
                                                const float* __restrict__ bg2,
                                                u16* __restrict__ CG){
  __shared__ float xs[64][16];
  int blk = blockIdx.x;
  int b = blk >> 7, r7 = blk & 127;
  int c = r7 >> 2, q = r7 & 3;
  int col = q * 256 + threadIdx.x;
  int tok0 = b * L_SEQ + c * 64;
  {
    int row = threadIdx.x >> 2, e4 = (threadIdx.x & 3) * 4;
    *(float4*)&xs[row][e4] = *(const float4*)&xg1[(size_t)(tok0 + row) * 16 + e4];
  }
  __syncthreads();
  float w[16];
  #pragma unroll
  for (int r = 0; r < 16; r++) w[r] = Wg2[r * HID + col];
  float bz = bg2[col];
  float cum = 0.f;
  for (int t = 0; t < 64; t++){
    float z = bz;
    #pragma unroll
    for (int r = 0; r < 16; r++) z += xs[t][r] * w[r];
    float ls = -__logf(1.f + __expf(-z));     // log_sigmoid, native ops (|z| small here)
    cum += ls * (1.0f / 16.0f);
    CG[(size_t)(tok0 + t) * HID + col] = f2bf(cum);
  }
}

// ---------------- QKVG GEMM: 256x128 tile, 512 thr / 8 waves (unchanged) ----------------
__global__ __launch_bounds__(512) void gla_gemm_qkvg(const u16* __restrict__ A,
                                                     const u16* __restrict__ Bt,
                                                     u16* __restrict__ C){
  constexpr int NT = HID / 32;
  __shared__ u16 As[2][256 * 32];
  __shared__ u16 Bs[2][128 * 32];
  const int tid = threadIdx.x;
  const int lane = tid & 63, wid = tid >> 6;
  const int wm = wid >> 1, wn = wid & 1;
  const int lr = lane & 15, lk = lane >> 4;
  const int id = blockIdx.x + 16 * blockIdx.y;
  const int nid = (id & 7) * 64 + (id >> 3);
  const int bm = nid & 15, bn = nid >> 4;
  const int srow = tid >> 2;
  const int skw  = ((tid & 3) * 8) ^ ((srow & 3) << 3);
  const u16* Ag = A  + ((size_t)bm * 256 + srow) * HID + skw;
  const u16* Bg = Bt + ((size_t)bn * 128 + srow) * HID + skw;

  f32x4 acc[4][4];
  #pragma unroll
  for (int i = 0; i < 4; i++)
    #pragma unroll
    for (int j = 0; j < 4; j++)
      #pragma unroll
      for (int e = 0; e < 4; e++) acc[i][j][e] = 0.f;

  auto STAGE = [&](int buf, int kt){
    gload_lds16(Ag + kt * 32,                         &As[buf][tid * 8]);
    gload_lds16(Ag + (size_t)128 * HID + kt * 32,     &As[buf][4096 + tid * 8]);
    gload_lds16(Bg + kt * 32,                         &Bs[buf][tid * 8]);
  };

  STAGE(0, 0);
  for (int t = 0; t < NT; ++t){
    const int buf = t & 1;
    if (t + 1 < NT){
      STAGE(buf ^ 1, t + 1);
      asm volatile("s_waitcnt vmcnt(3)\ns_barrier" ::: "memory");
    } else {
      asm volatile("s_waitcnt vmcnt(0)\ns_barrier" ::: "memory");
    }
    bf16x8 af[4], bfr[4];
    #pragma unroll
    for (int m = 0; m < 4; m++){
      int row = wm * 64 + m * 16 + lr;
      af[m] = *(const bf16x8*)&As[buf][(row * 32 + lk * 8) ^ ((row & 3) << 3)];
    }
    #pragma unroll
    for (int n = 0; n < 4; n++){
      int row = wn * 64 + n * 16 + lr;
      bfr[n] = *(const bf16x8*)&Bs[buf][(row * 32 + lk * 8) ^ ((row & 3) << 3)];
    }
    __builtin_amdgcn_s_setprio(1);
    #pragma unroll
    for (int m = 0; m < 4; m++)
      #pragma unroll
      for (int n = 0; n < 4; n++)
        acc[m][n] = __builtin_amdgcn_mfma_f32_16x16x32_bf16(af[m], bfr[n], acc[m][n], 0, 0, 0);
    __builtin_amdgcn_s_setprio(0);
    __builtin_amdgcn_sched_barrier(0);
    asm volatile("s_barrier" ::: "memory");
  }

  #pragma unroll
  for (int i = 0; i < 4; i++)
    #pragma unroll
    for (int j = 0; j < 4; j++){
      int row0 = bm * 256 + wm * 64 + i * 16 + lk * 4;
      int cb   = bn * 128 + wn * 64 + j * 16 + lr;
      int sel  = cb >> 10, col = cb & 1023;
      size_t base = (size_t)sel * ((size_t)MTOK * HID) + (size_t)row0 * HID + col;
      #pragma unroll
      for (int r = 0; r < 4; r++)
        C[base + (size_t)r * HID] = f2bf(acc[i][j][r]);
    }
}

// ---------------- out GEMM v2: 64x128 tiles, 512 blocks, 256 thr, wave-pair split-K ------
__global__ __launch_bounds__(256) void gla_gemm_out2(const u16* __restrict__ A,
                                                     const u16* __restrict__ Bt,
                                                     float* __restrict__ C){
  constexpr int NT = 16;                  // 512 / 32 per K-group
  __shared__ __align__(16) char smem[49152];   // [kg][buf]: A 4KB + B 8KB; reduce aliases
  const int tid = threadIdx.x;
  const int lane = tid & 63, wid = tid >> 6;
  const int kg = wid >> 1, w = wid & 1;   // waves 0-1: K[0:512]; waves 2-3: K[512:1024]
  const int lr = lane & 15, lk = lane >> 4;
  const int bm = blockIdx.x, bn = blockIdx.y;
  const int srow = tid >> 2;
  const int skw  = ((tid & 3) * 8) ^ ((srow & 3) << 3);
  const u16* Ag = A  + ((size_t)bm * 64  + srow) * HID + skw;
  const u16* Bg = Bt + ((size_t)bn * 128 + srow) * HID + skw;
  auto seg = [&](int g, int buf) -> u16* { return (u16*)(smem + (g * 2 + buf) * 12288); };

  f32x4 acc[4][4];
  #pragma unroll
  for (int i = 0; i < 4; i++)
    #pragma unroll
    for (int j = 0; j < 4; j++)
      #pragma unroll
      for (int e = 0; e < 4; e++) acc[i][j][e] = 0.f;

  auto STAGE = [&](int buf, int kt){
    gload_lds16(Ag + kt * 32,                          seg(0, buf) + tid * 8);
    gload_lds16(Bg + kt * 32,                          seg(0, buf) + 2048 + tid * 8);
    gload_lds16(Bg + (size_t)64 * HID + kt * 32,       seg(0, buf) + 4096 + tid * 8);
    gload_lds16(Ag + 512 + kt * 32,                    seg(1, buf) + tid * 8);
    gload_lds16(Bg + 512 + kt * 32,                    seg(1, buf) + 2048 + tid * 8);
    gload_lds16(Bg + (size_t)64 * HID + 512 + kt * 32, seg(1, buf) + 4096 + tid * 8);
  };

  STAGE(0, 0);
  for (int t = 0; t < NT; ++t){
    const int buf = t & 1;
    if (t + 1 < NT){
      STAGE(buf ^ 1, t + 1);
      asm volatile("s_waitcnt vmcnt(6)\ns_barrier" ::: "memory");
    } else {
      asm volatile("s_waitcnt vmcnt(0)\ns_barrier" ::: "memory");
    }
    const u16* Ab = seg(kg, buf);
    const u16* Bb = seg(kg, buf) + 2048;
    bf16x8 af[4], bfr[4];
    #pragma unroll
    for (int m = 0; m < 4; m++){
      int row = m * 16 + lr;
      af[m] = *(const bf16x8*)&Ab[(row * 32 + lk * 8) ^ ((row & 3) << 3)];
    }
    #pragma unroll
    for (int n = 0; n < 4; n++){
      int row = w * 64 + n * 16 + lr;
      bfr[n] = *(const bf16x8*)&Bb[(row * 32 + lk * 8) ^ ((row & 3) << 3)];
    }
    __builtin_amdgcn_s_setprio(1);
    #pragma unroll
    for (int m = 0; m < 4; m++)
      #pragma unroll
      for (int n = 0; n < 4; n++)
        acc[m][n] = __builtin_amdgcn_mfma_f32_16x16x32_bf16(af[m], bfr[n], acc[m][n], 0, 0, 0);
    __builtin_amdgcn_s_setprio(0);
    __builtin_amdgcn_sched_barrier(0);
    asm volatile("s_barrier" ::: "memory");
  }

  float* red = (float*)smem;              // 64 x 132 f32 = 33.8KB, aliases staging (dead)
  if (kg == 1){
    #pragma unroll
    for (int m = 0; m < 4; m++)
      #pragma unroll
      for (int n = 0; n < 4; n++){
        int lrow = m * 16 + lk * 4, lcol = w * 64 + n * 16 + lr;
        #pragma unroll
        for (int r = 0; r < 4; r++)
          red[(lrow + r) * 132 + lcol] = acc[m][n][r];
      }
  }
  __syncthreads();
  if (kg == 0){
    #pragma unroll
    for (int m = 0; m < 4; m++)
      #pragma unroll
      for (int n = 0; n < 4; n++){
        int lrow = m * 16 + lk * 4, lcol = w * 64 + n * 16 + lr;
        #pragma unroll
        for (int r = 0; r < 4; r++)
          C[(size_t)(bm * 64 + lrow + r) * HID + bn * 128 + lcol] =
              acc[m][n][r] + red[(lrow + r) * 132 + lcol];
      }
  }
}

// ---------------- pass B (MFMA): T_c = K^hat^T @ V (bf16 out), D_c = exp(cg_last) -------
__global__ __launch_bounds__(256) void gla_chunk_state2(const u16* __restrict__ Kb,
                                                        const u16* __restrict__ Vb,
                                                        const u16* __restrict__ CG,
                                                        u16* __restrict__ Tbuf,
                                                        float* __restrict__ Dbuf){
  __shared__ u16 KHT[64 * 72];
  __shared__ u16 VT[64 * 72];
  int blk = blockIdx.x;
  int c = blk & (NC - 1), bh = blk >> 5;
  int b = bh >> 4, h = bh & 15;
  int tid = threadIdx.x;
  int lane = tid & 63, w = tid >> 6;
  int lr = lane & 15, lk = lane >> 4;
  int tr = tid >> 2, tc = (tid & 3) * 16;
  size_t gbase = ((size_t)(b * L_SEQ + c * 64)) * HID + h * 64;

  float cg[16], cgl[16];
  {
    const u16* cgp = CG + gbase + (size_t)tr * HID + tc;
    const u16* clp = CG + gbase + (size_t)63 * HID + tc;
    uint4 a0 = *(const uint4*)cgp, a1 = *(const uint4*)(cgp + 8);
    uint4 l0 = *(const uint4*)clp, l1 = *(const uint4*)(clp + 8);
    const u16* au = (const u16*)&a0; const u16* au2 = (const u16*)&a1;
    const u16* lu = (const u16*)&l0; const u16* lu2 = (const u16*)&l1;
    #pragma unroll
    for (int e = 0; e < 8; e++){
      cg[e] = bf2f(au[e]); cg[8 + e] = bf2f(au2[e]);
      cgl[e] = bf2f(lu[e]); cgl[8 + e] = bf2f(lu2[e]);
    }
  }
  {
    const u16* kp = Kb + gbase + (size_t)tr * HID + tc;
    const u16* vp = Vb + gbase + (size_t)tr * HID + tc;
    uint4 kr0 = *(const uint4*)kp, kr1 = *(const uint4*)(kp + 8);
    uint4 vr0 = *(const uint4*)vp, vr1 = *(const uint4*)(vp + 8);
    const u16* ku = (const u16*)&kr0; const u16* ku2 = (const u16*)&kr1;
    const u16* vu = (const u16*)&vr0; const u16* vu2 = (const u16*)&vr1;
    #pragma unroll
    for (int e = 0; e < 8; e++){
      KHT[swz72(tc + e, tr)]     = f2bf(bf2f(ku[e])  * __expf(cgl[e]     - cg[e]));
      KHT[swz72(tc + 8 + e, tr)] = f2bf(bf2f(ku2[e]) * __expf(cgl[8 + e] - cg[8 + e]));
      VT[swz72(tc + e, tr)]      = vu[e];
      VT[swz72(tc + 8 + e, tr)]  = vu2[e];
    }
  }
  if (tr == 0){
    #pragma unroll
    for (int e = 0; e < 16; e++)
      Dbuf[(size_t)blk * 64 + tc + e] = __expf(cgl[e]);
  }
  __syncthreads();
  int R0 = w * 16;
  f32x4 tacc[4];
  #pragma unroll
  for (int v = 0; v < 4; v++)
    #pragma unroll
    for (int e = 0; e < 4; e++) tacc[v][e] = 0.f;
  #pragma unroll
  for (int ks = 0; ks < 2; ks++){
    bf16x8 a = *(const bf16x8*)&KHT[swz72(R0 + lr, ks * 32 + lk * 8)];
    #pragma unroll
    for (int v0 = 0; v0 < 4; v0++){
      bf16x8 bb = *(const bf16x8*)&VT[swz72(v0 * 16 + lr, ks * 32 + lk * 8)];
      tacc[v0] = __builtin_amdgcn_mfma_f32_16x16x32_bf16(a, bb, tacc[v0], 0, 0, 0);
    }
  }
  u16* Tp = Tbuf + (size_t)blk * 4096;
  #pragma unroll
  for (int v0 = 0; v0 < 4; v0++){
    int d = R0 + lk * 4, v = v0 * 16 + lr;
    #pragma unroll
    for (int r = 0; r < 4; r++)
      Tp[(d + r) * 64 + v] = f2bf(tacc[v0][r]);
  }
}

// ---------------- pass C: parallel chunk-state scan (bf16 T in, bf16 S_in out) ----------
__global__ __launch_bounds__(256) void gla_state_scan2(const u16* __restrict__ Tbuf,
                                                       const float* __restrict__ Dbuf,
                                                       float* __restrict__ Sfin,
                                                       u16* __restrict__ Sinb){
  int bh = blockIdx.x >> 4, seg = blockIdx.x & 15;
  int dv = seg * 256 + threadIdx.x;
  int d = dv >> 6;
  float S = 0.f;
  for (int c = 0; c < NC; c++){
    size_t slot = (size_t)bh * NC + c;
    float t  = bf2f(Tbuf[slot * 4096 + dv]);
    float dec = Dbuf[slot * 64 + d];
    Sinb[slot * 4096 + dv] = f2bf(S);
    S = dec * S + t;
  }
  Sfin[(size_t)bh * 4096 + dv] = S;
}

// ---------------- pass D (MFMA): outputs + RMSNorm + swish gate (3-barrier version) -----
__global__ __launch_bounds__(256) void gla_chunk_out2(const u16* __restrict__ Qb,
                                                      const u16* __restrict__ Kb,
                                                      const u16* __restrict__ Vb,
                                                      const u16* __restrict__ CG,
                                                      const u16* __restrict__ Sinb,
                                                      const u16* __restrict__ Gb,
                                                      const float* __restrict__ gnw,
                                                      u16* __restrict__ OG){
  __shared__ u16 QT[64 * 72];   // q~ rows t cols d; epilogue reuses as out-stage (wave-local)
  __shared__ u16 KP[64 * 72];   // k~ rows j cols d; after S2 reused for masked P (wave-local)
  __shared__ u16 VT[64 * 72];   // V^T rows v cols t (swz72)
  __shared__ u16 ST[64 * 72];   // S^T rows v cols d (swz72)
  int blk = blockIdx.x;
  int c = blk & (NC - 1), bh = blk >> 5;
  int b = bh >> 4, h = bh & 15;
  int tid = threadIdx.x;
  int lane = tid & 63, w = tid >> 6;
  int lr = lane & 15, lk = lane >> 4;
  int tr = tid >> 2, tc = (tid & 3) * 16;
  size_t gbase = ((size_t)(b * L_SEQ + c * 64)) * HID + h * 64;

  // ---- stage q~, k~, V^T, S^T ----
  {
    float cg[16];
    const u16* cgp = CG + gbase + (size_t)tr * HID + tc;
    uint4 a0 = *(const uint4*)cgp, a1 = *(const uint4*)(cgp + 8);
    const u16* au = (const u16*)&a0; const u16* au2 = (const u16*)&a1;
    #pragma unroll
    for (int e = 0; e < 8; e++){ cg[e] = bf2f(au[e]); cg[8 + e] = bf2f(au2[e]); }
    const u16* qp = Qb + gbase + (size_t)tr * HID + tc;
    const u16* kp = Kb + gbase + (size_t)tr * HID + tc;
    const u16* vp = Vb + gbase + (size_t)tr * HID + tc;
    uint4 qr0 = *(const uint4*)qp, qr1 = *(const uint4*)(qp + 8);
    uint4 kr0 = *(const uint4*)kp, kr1 = *(const uint4*)(kp + 8);
    uint4 vr0 = *(const uint4*)vp, vr1 = *(const uint4*)(vp + 8);
    const u16* qu = (const u16*)&qr0; const u16* qu2 = (const u16*)&qr1;
    const u16* ku = (const u16*)&kr0; const u16* ku2 = (const u16*)&kr1;
    const u16* vu = (const u16*)&vr0; const u16* vu2 = (const u16*)&vr1;
    u16 qt[16] __attribute__((aligned(16)));
    u16 kt[16] __attribute__((aligned(16)));
    #pragma unroll
    for (int e = 0; e < 8; e++){
      float ec0 = __expf(cg[e]),  ei0 = __expf(-cg[e]);
      float ec1 = __expf(cg[8+e]), ei1 = __expf(-cg[8+e]);
      qt[e]     = f2bf(bf2f(qu[e])  * ec0 * QSCALE);
      qt[8 + e] = f2bf(bf2f(qu2[e]) * ec1 * QSCALE);
      kt[e]     = f2bf(bf2f(ku[e])  * ei0);
      kt[8 + e] = f2bf(bf2f(ku2[e]) * ei1);
      VT[swz72(tc + e, tr)]     = vu[e];
      VT[swz72(tc + 8 + e, tr)] = vu2[e];
    }
    *(uint4*)&QT[tr * 72 + tc]     = *(uint4*)&qt[0];
    *(uint4*)&QT[tr * 72 + tc + 8] = *(uint4*)&qt[8];
    *(uint4*)&KP[tr * 72 + tc]     = *(uint4*)&kt[0];
    *(uint4*)&KP[tr * 72 + tc + 8] = *(uint4*)&kt[8];
    const u16* sp = Sinb + (size_t)blk * 4096 + (size_t)tr * 64 + tc;
    uint4 s0 = *(const uint4*)sp, s1 = *(const uint4*)(sp + 8);
    const u16* su = (const u16*)&s0; const u16* su2 = (const u16*)&s1;
    #pragma unroll
    for (int e = 0; e < 8; e++){
      ST[swz72(tc + e, tr)]     = su[e];
      ST[swz72(tc + 8 + e, tr)] = su2[e];
    }
  }
  __syncthreads();                             // S1: staging visible

  // ---- matmul 1: P = q~ @ k~^T ----
  int R0 = w * 16;
  f32x4 pacc[4];
  #pragma unroll
  for (int j = 0; j < 4; j++)
    #pragma unroll
    for (int e = 0; e < 4; e++) pacc[j][e] = 0.f;
  #pragma unroll
  for (int ks = 0; ks < 2; ks++){
    bf16x8 a = *(const bf16x8*)&QT[(R0 + lr) * 72 + ks * 32 + lk * 8];
    #pragma unroll
    for (int j0 = 0; j0 < 4; j0++){
      bf16x8 bb = *(const bf16x8*)&KP[(j0 * 16 + lr) * 72 + ks * 32 + lk * 8];
      pacc[j0] = __builtin_amdgcn_mfma_f32_16x16x32_bf16(a, bb, pacc[j0], 0, 0, 0);
    }
  }
  __syncthreads();                             // S2: all waves done reading KP (k~)

  // ---- masked P into KP (wave-local rows -> no barrier before mm2) ----
  #pragma unroll
  for (int j0 = 0; j0 < 4; j0++){
    int j = j0 * 16 + lr;
    #pragma unroll
    for (int r = 0; r < 4; r++){
      int t = R0 + lk * 4 + r;
      KP[t * 72 + (j ^ swzc(t))] = (j <= t) ? f2bf(pacc[j0][r]) : (u16)0;
    }
  }

  // ---- matmul 3 (q~ @ S^T) + matmul 2 (P @ V^T) ----
  f32x4 oacc[4];
  #pragma unroll
  for (int v = 0; v < 4; v++)
    #pragma unroll
    for (int e = 0; e < 4; e++) oacc[v][e] = 0.f;
  #pragma unroll
  for (int ks = 0; ks < 2; ks++){
    bf16x8 a = *(const bf16x8*)&QT[(R0 + lr) * 72 + ks * 32 + lk * 8];
    #pragma unroll
    for (int v0 = 0; v0 < 4; v0++){
      bf16x8 bb = *(const bf16x8*)&ST[swz72(v0 * 16 + lr, ks * 32 + lk * 8)];
      oacc[v0] = __builtin_amdgcn_mfma_f32_16x16x32_bf16(a, bb, oacc[v0], 0, 0, 0);
    }
  }
  #pragma unroll
  for (int ks = 0; ks < 2; ks++){
    int arow = R0 + lr;
    bf16x8 a = *(const bf16x8*)&KP[arow * 72 + ((ks * 32 + lk * 8) ^ swzc(arow))];
    #pragma unroll
    for (int v0 = 0; v0 < 4; v0++){
      bf16x8 bb = *(const bf16x8*)&VT[swz72(v0 * 16 + lr, ks * 32 + lk * 8)];
      oacc[v0] = __builtin_amdgcn_mfma_f32_16x16x32_bf16(a, bb, oacc[v0], 0, 0, 0);
    }
  }

  // ---- epilogue: RMSNorm + affine + swish (gate direct from global); stage into QT ----
  {
    float gv[4][4];
    #pragma unroll
    for (int r = 0; r < 4; r++){
      int t = R0 + lk * 4 + r;
      #pragma unroll
      for (int v0 = 0; v0 < 4; v0++)
        gv[r][v0] = bf2f(Gb[gbase + (size_t)t * HID + v0 * 16 + lr]);
    }
    float gnv[4];
    #pragma unroll
    for (int v0 = 0; v0 < 4; v0++) gnv[v0] = gnw[v0 * 16 + lr];
    #pragma unroll
    for (int r = 0; r < 4; r++){
      float ssq = 0.f;
      #pragma unroll
      for (int v0 = 0; v0 < 4; v0++) ssq += oacc[v0][r] * oacc[v0][r];
      ssq += __shfl_xor(ssq, 1, 64);
      ssq += __shfl_xor(ssq, 2, 64);
      ssq += __shfl_xor(ssq, 4, 64);
      ssq += __shfl_xor(ssq, 8, 64);
      float rn = rsqrtf(ssq * (1.0f / 64.0f) + GEPS);
      int t = R0 + lk * 4 + r;
      #pragma unroll
      for (int v0 = 0; v0 < 4; v0++){
        float g = gv[r][v0];
        float sw = g / (1.f + __expf(-g));
        QT[t * 72 + ((v0 * 16 + lr) ^ swzc(t))] = f2bf(oacc[v0][r] * rn * gnv[v0] * sw);
      }
    }
  }
  __syncthreads();                             // S3: out-stage visible
  {
    int x0 = swzc(tr);
    uint4 o0 = *(uint4*)&QT[tr * 72 + (tc ^ x0)];
    uint4 o1 = *(uint4*)&QT[tr * 72 + ((tc + 8) ^ x0)];
    u16* op = OG + gbase + (size_t)tr * HID + tc;
    *(uint4*)op       = o0;
    *(uint4*)(op + 8) = o1;
  }
}

// ---------------- host launcher ----------------
extern "C" void kernel_launch(void* const* d_in, const int* in_sizes, int n_in,
                              void* d_out, int out_size, void* d_ws, size_t ws_size,
                              hipStream_t stream){
  (void)in_sizes; (void)n_in; (void)out_size;
  const float* x   = (const float*)d_in[0];
  const float* Wq  = (const float*)d_in[1];
  const float* Wk  = (const float*)d_in[2];
  const float* Wv  = (const float*)d_in[3];
  const float* Wg1 = (const float*)d_in[4];
  const float* Wg2 = (const float*)d_in[5];
  const float* bg2 = (const float*)d_in[6];
  const float* Wg  = (const float*)d_in[7];
  const float* gnw = (const float*)d_in[8];
  const float* Wo  = (const float*)d_in[9];
  float* out = (float*)d_out;

  char* ws = (char*)d_ws;
  size_t off = 0;
  auto alloc = [&](size_t bytes) -> char* {
    char* p = ws + off; off += (bytes + 255) & ~(size_t)255; return p;
  };
  u16* xb   = (u16*)alloc((size_t)MTOK * HID * 2);
  u16* WTq  = (u16*)alloc((size_t)HID * HID * 2);   // WTq..WTg contiguous: combined N=4096
  u16* WTk  = (u16*)alloc((size_t)HID * HID * 2);
  u16* WTv  = (u16*)alloc((size_t)HID * HID * 2);
  u16* WTg  = (u16*)alloc((size_t)HID * HID * 2);
  u16* WTo  = (u16*)alloc((size_t)HID * HID * 2);
  u16* Qb   = (u16*)alloc((size_t)MTOK * HID * 2);  // Qb..Gb contiguous: sel-strided C
  u16* Kb   = (u16*)alloc((size_t)MTOK * HID * 2);
  u16* Vb   = (u16*)alloc((size_t)MTOK * HID * 2);
  u16* Gb   = (u16*)alloc((size_t)MTOK * HID * 2);
  u16* CGb  = (u16*)alloc((size_t)MTOK * HID * 2);
  float* xg1b = (float*)alloc((size_t)MTOK * 16 * 4);
  u16* Tbuf = (u16*)alloc((size_t)1024 * 4096 * 2);
  float* Dbuf = (float*)alloc((size_t)1024 * 64 * 4);
  u16* Sinb = (u16*)alloc((size_t)1024 * 4096 * 2);
  u16* OG   = (u16*)alloc((size_t)MTOK * HID * 2);
  if (off > ws_size) return;

  gla_prep<<<6144, 256, 0, stream>>>(x, Wg1, xg1b, xb, Wq, Wk, Wv, Wg, Wo,
                                     WTq, WTk, WTv, WTg, WTo);
  gla_gkcg<<<256, 256, 0, stream>>>(xg1b, Wg2, bg2, CGb);

  dim3 gq(16, 32);
  gla_gemm_qkvg<<<gq, 512, 0, stream>>>(xb, WTq, Qb);   // Q,K,V,G in one dispatch

  gla_chunk_state2<<<1024, 256, 0, stream>>>(Kb, Vb, CGb, Tbuf, Dbuf);
  gla_state_scan2<<<512, 256, 0, stream>>>(Tbuf, Dbuf, out + (size_t)MTOK * HID, Sinb);
  gla_chunk_out2<<<1024, 256, 0, stream>>>(Qb, Kb, Vb, CGb, Sinb, Gb, gnw, OG);

  dim3 go(64, 8);
  gla_gemm_out2<<<go, 256, 0, stream>>>(OG, WTo, out);
}

// Round 8
// 118.553 us; speedup vs baseline: 1.3304x; 1.1458x over previous
//
#include <hip/hip_runtime.h>
#include <hip/hip_bf16.h>

typedef unsigned short u16;
typedef __attribute__((ext_vector_type(8))) short bf16x8;
typedef __attribute__((ext_vector_type(4))) float f32x4;

#define L_SEQ 2048
#define HID 1024
#define NC 32
#define MTOK 4096
#define GEPS 1e-5f
#define QSCALE 0.125f

__device__ __forceinline__ float bf2f(u16 u){ union{unsigned i; float f;}c; c.i=(unsigned)u<<16; return c.f; }
__device__ __forceinline__ u16 f2bf(float f){ union{__hip_bfloat16 h; u16 u;}c; c.h=__float2bfloat16(f); return c.u; }

// transposed-LDS swizzle (rows 16 apart alias banks): XOR col bits 3..4 with row bits 4..5.
__device__ __forceinline__ int swz72(int row, int col){ return row * 72 + (col ^ ((row >> 1) & 24)); }
// C-fragment-shaped scatter swizzle: rows t = base+4*lk+r -> XOR by 8*lk spreads banks.
__device__ __forceinline__ int swzc(int t){ return ((t >> 2) & 3) << 3; }

__device__ __forceinline__ void gload_lds16(const u16* g, u16* l){
  __builtin_amdgcn_global_load_lds((const __attribute__((address_space(1))) void*)g,
                                   (__attribute__((address_space(3))) void*)l, 16, 0, 0);
}

// ---------------- prep: xb = bf16(x) (streaming) + 5 weight transposes ----------------
__global__ __launch_bounds__(256) void gla_prep(const float* __restrict__ x,
                                                u16* __restrict__ xb,
                                                const float* W0, const float* W1,
                                                const float* W2, const float* W3,
                                                const float* W4,
                                                u16* D0, u16* D1, u16* D2, u16* D3, u16* D4){
  __shared__ float tile[32][33];
  int bid = blockIdx.x;
  if (bid < 2048){
    size_t i = ((size_t)bid * 256 + threadIdx.x) * 8;
    float4 a = *(const float4*)&x[i];
    float4 b = *(const float4*)&x[i + 4];
    u16 o[8] __attribute__((aligned(16))) = {
      f2bf(a.x), f2bf(a.y), f2bf(a.z), f2bf(a.w),
      f2bf(b.x), f2bf(b.y), f2bf(b.z), f2bf(b.w) };
    *(uint4*)&xb[i] = *(uint4*)o;
  } else {
    int id = bid - 2048;
    int z = id >> 10, rem = id & 1023;
    int bx = rem & 31, by = rem >> 5;
    const float* W; u16* D;
    switch (z){
      case 0: W = W0; D = D0; break;
      case 1: W = W1; D = D1; break;
      case 2: W = W2; D = D2; break;
      case 3: W = W3; D = D3; break;
      default: W = W4; D = D4; break;
    }
    int tx = threadIdx.x & 31, ty = threadIdx.x >> 5;
    int n0 = bx * 32, k0 = by * 32;
    #pragma unroll
    for (int r = ty; r < 32; r += 8)
      tile[r][tx] = W[(size_t)(k0 + r) * HID + n0 + tx];
    __syncthreads();
    #pragma unroll
    for (int r = ty; r < 32; r += 8)
      D[(size_t)(n0 + r) * HID + k0 + tx] = f2bf(tile[tx][r]);
  }
}

// ---------------- xg1 = xb @ Wg1 via MFMA (4096x16x1024) ----------------
// 64 blocks x 4 waves; wave = one 16-row tile, full K. Wg1^T staged bf16 in LDS.
__global__ __launch_bounds__(256) void gla_xg1_mfma(const u16* __restrict__ xb,
                                                    const float* __restrict__ Wg1,
                                                    float* __restrict__ xg1){
  __shared__ u16 WL[16 * 1032];     // Wg1^T: row n (out col), col k; +8 pad
  #pragma unroll 8
  for (int i = 0; i < 64; i++){
    int flat = i * 256 + threadIdx.x;     // coalesced f32 read
    int k = flat >> 4, n = flat & 15;
    WL[n * 1032 + k] = f2bf(Wg1[flat]);
  }
  __syncthreads();
  int lane = threadIdx.x & 63, w = threadIdx.x >> 6;
  int lr = lane & 15, lk = lane >> 4;
  int rt = blockIdx.x * 4 + w;            // row-tile 0..255
  const u16* Arow = xb + ((size_t)rt * 16 + lr) * HID;
  f32x4 acc;
  #pragma unroll
  for (int e = 0; e < 4; e++) acc[e] = 0.f;
  #pragma unroll 4
  for (int ks = 0; ks < 32; ks++){
    bf16x8 a = *(const bf16x8*)&Arow[ks * 32 + lk * 8];
    bf16x8 b = *(const bf16x8*)&WL[lr * 1032 + ks * 32 + lk * 8];
    acc = __builtin_amdgcn_mfma_f32_16x16x32_bf16(a, b, acc, 0, 0, 0);
  }
  #pragma unroll
  for (int r = 0; r < 4; r++)
    xg1[(size_t)(rt * 16 + lk * 4 + r) * 16 + lr] = acc[r];
}

// ---------------- gate stage 2 + per-chunk cumsum: CG (bf16) ----------------
__global__ __launch_bounds__(256) void gla_gkcg(const float* __restrict__ xg1,
                                                const float* __restrict__ Wg2,
                                                const float* __restrict__ bg2,
                                                u16* __restrict__ CG){
  __shared__ float xs[64][16];
  int blk = blockIdx.x;
  int b = blk >> 7, r7 = blk & 127;
  int c = r7 >> 2, q = r7 & 3;
  int col = q * 256 + threadIdx.x;
  int tok0 = b * L_SEQ + c * 64;
  {
    int row = threadIdx.x >> 2, e4 = (threadIdx.x & 3) * 4;
    *(float4*)&xs[row][e4] = *(const float4*)&xg1[(size_t)(tok0 + row) * 16 + e4];
  }
  __syncthreads();
  float w[16];
  #pragma unroll
  for (int r = 0; r < 16; r++) w[r] = Wg2[r * HID + col];
  float bz = bg2[col];
  float cum = 0.f;
  for (int t = 0; t < 64; t++){
    float z = bz;
    #pragma unroll
    for (int r = 0; r < 16; r++) z += xs[t][r] * w[r];
    float ls = -__logf(1.f + __expf(-z));
    cum += ls * (1.0f / 16.0f);
    CG[(size_t)(tok0 + t) * HID + col] = f2bf(cum);
  }
}

// ---------------- QKVG GEMM: 256x128 tile, 512 thr / 8 waves ----------------
__global__ __launch_bounds__(512) void gla_gemm_qkvg(const u16* __restrict__ A,
                                                     const u16* __restrict__ Bt,
                                                     u16* __restrict__ C){
  constexpr int NT = HID / 32;
  __shared__ u16 As[2][256 * 32];
  __shared__ u16 Bs[2][128 * 32];
  const int tid = threadIdx.x;
  const int lane = tid & 63, wid = tid >> 6;
  const int wm = wid >> 1, wn = wid & 1;
  const int lr = lane & 15, lk = lane >> 4;
  const int id = blockIdx.x + 16 * blockIdx.y;
  const int nid = (id & 7) * 64 + (id >> 3);
  const int bm = nid & 15, bn = nid >> 4;
  const int srow = tid >> 2;
  const int skw  = ((tid & 3) * 8) ^ ((srow & 3) << 3);
  const u16* Ag = A  + ((size_t)bm * 256 + srow) * HID + skw;
  const u16* Bg = Bt + ((size_t)bn * 128 + srow) * HID + skw;

  f32x4 acc[4][4];
  #pragma unroll
  for (int i = 0; i < 4; i++)
    #pragma unroll
    for (int j = 0; j < 4; j++)
      #pragma unroll
      for (int e = 0; e < 4; e++) acc[i][j][e] = 0.f;

  auto STAGE = [&](int buf, int kt){
    gload_lds16(Ag + kt * 32,                         &As[buf][tid * 8]);
    gload_lds16(Ag + (size_t)128 * HID + kt * 32,     &As[buf][4096 + tid * 8]);
    gload_lds16(Bg + kt * 32,                         &Bs[buf][tid * 8]);
  };

  STAGE(0, 0);
  for (int t = 0; t < NT; ++t){
    const int buf = t & 1;
    if (t + 1 < NT){
      STAGE(buf ^ 1, t + 1);
      asm volatile("s_waitcnt vmcnt(3)\ns_barrier" ::: "memory");
    } else {
      asm volatile("s_waitcnt vmcnt(0)\ns_barrier" ::: "memory");
    }
    bf16x8 af[4], bfr[4];
    #pragma unroll
    for (int m = 0; m < 4; m++){
      int row = wm * 64 + m * 16 + lr;
      af[m] = *(const bf16x8*)&As[buf][(row * 32 + lk * 8) ^ ((row & 3) << 3)];
    }
    #pragma unroll
    for (int n = 0; n < 4; n++){
      int row = wn * 64 + n * 16 + lr;
      bfr[n] = *(const bf16x8*)&Bs[buf][(row * 32 + lk * 8) ^ ((row & 3) << 3)];
    }
    __builtin_amdgcn_s_setprio(1);
    #pragma unroll
    for (int m = 0; m < 4; m++)
      #pragma unroll
      for (int n = 0; n < 4; n++)
        acc[m][n] = __builtin_amdgcn_mfma_f32_16x16x32_bf16(af[m], bfr[n], acc[m][n], 0, 0, 0);
    __builtin_amdgcn_s_setprio(0);
    __builtin_amdgcn_sched_barrier(0);
    asm volatile("s_barrier" ::: "memory");
  }

  #pragma unroll
  for (int i = 0; i < 4; i++)
    #pragma unroll
    for (int j = 0; j < 4; j++){
      int row0 = bm * 256 + wm * 64 + i * 16 + lk * 4;
      int cb   = bn * 128 + wn * 64 + j * 16 + lr;
      int sel  = cb >> 10, col = cb & 1023;
      size_t base = (size_t)sel * ((size_t)MTOK * HID) + (size_t)row0 * HID + col;
      #pragma unroll
      for (int r = 0; r < 4; r++)
        C[base + (size_t)r * HID] = f2bf(acc[i][j][r]);
    }
}

// ---------------- out GEMM v2: 64x128 tiles, 512 blocks, 256 thr, wave-pair split-K ------
__global__ __launch_bounds__(256) void gla_gemm_out2(const u16* __restrict__ A,
                                                     const u16* __restrict__ Bt,
                                                     float* __restrict__ C){
  constexpr int NT = 16;
  __shared__ __align__(16) char smem[49152];
  const int tid = threadIdx.x;
  const int lane = tid & 63, wid = tid >> 6;
  const int kg = wid >> 1, w = wid & 1;
  const int lr = lane & 15, lk = lane >> 4;
  const int bm = blockIdx.x, bn = blockIdx.y;
  const int srow = tid >> 2;
  const int skw  = ((tid & 3) * 8) ^ ((srow & 3) << 3);
  const u16* Ag = A  + ((size_t)bm * 64  + srow) * HID + skw;
  const u16* Bg = Bt + ((size_t)bn * 128 + srow) * HID + skw;
  auto seg = [&](int g, int buf) -> u16* { return (u16*)(smem + (g * 2 + buf) * 12288); };

  f32x4 acc[4][4];
  #pragma unroll
  for (int i = 0; i < 4; i++)
    #pragma unroll
    for (int j = 0; j < 4; j++)
      #pragma unroll
      for (int e = 0; e < 4; e++) acc[i][j][e] = 0.f;

  auto STAGE = [&](int buf, int kt){
    gload_lds16(Ag + kt * 32,                          seg(0, buf) + tid * 8);
    gload_lds16(Bg + kt * 32,                          seg(0, buf) + 2048 + tid * 8);
    gload_lds16(Bg + (size_t)64 * HID + kt * 32,       seg(0, buf) + 4096 + tid * 8);
    gload_lds16(Ag + 512 + kt * 32,                    seg(1, buf) + tid * 8);
    gload_lds16(Bg + 512 + kt * 32,                    seg(1, buf) + 2048 + tid * 8);
    gload_lds16(Bg + (size_t)64 * HID + 512 + kt * 32, seg(1, buf) + 4096 + tid * 8);
  };

  STAGE(0, 0);
  for (int t = 0; t < NT; ++t){
    const int buf = t & 1;
    if (t + 1 < NT){
      STAGE(buf ^ 1, t + 1);
      asm volatile("s_waitcnt vmcnt(6)\ns_barrier" ::: "memory");
    } else {
      asm volatile("s_waitcnt vmcnt(0)\ns_barrier" ::: "memory");
    }
    const u16* Ab = seg(kg, buf);
    const u16* Bb = seg(kg, buf) + 2048;
    bf16x8 af[4], bfr[4];
    #pragma unroll
    for (int m = 0; m < 4; m++){
      int row = m * 16 + lr;
      af[m] = *(const bf16x8*)&Ab[(row * 32 + lk * 8) ^ ((row & 3) << 3)];
    }
    #pragma unroll
    for (int n = 0; n < 4; n++){
      int row = w * 64 + n * 16 + lr;
      bfr[n] = *(const bf16x8*)&Bb[(row * 32 + lk * 8) ^ ((row & 3) << 3)];
    }
    __builtin_amdgcn_s_setprio(1);
    #pragma unroll
    for (int m = 0; m < 4; m++)
      #pragma unroll
      for (int n = 0; n < 4; n++)
        acc[m][n] = __builtin_amdgcn_mfma_f32_16x16x32_bf16(af[m], bfr[n], acc[m][n], 0, 0, 0);
    __builtin_amdgcn_s_setprio(0);
    __builtin_amdgcn_sched_barrier(0);
    asm volatile("s_barrier" ::: "memory");
  }

  float* red = (float*)smem;
  if (kg == 1){
    #pragma unroll
    for (int m = 0; m < 4; m++)
      #pragma unroll
      for (int n = 0; n < 4; n++){
        int lrow = m * 16 + lk * 4, lcol = w * 64 + n * 16 + lr;
        #pragma unroll
        for (int r = 0; r < 4; r++)
          red[(lrow + r) * 132 + lcol] = acc[m][n][r];
      }
  }
  __syncthreads();
  if (kg == 0){
    #pragma unroll
    for (int m = 0; m < 4; m++)
      #pragma unroll
      for (int n = 0; n < 4; n++){
        int lrow = m * 16 + lk * 4, lcol = w * 64 + n * 16 + lr;
        #pragma unroll
        for (int r = 0; r < 4; r++)
          C[(size_t)(bm * 64 + lrow + r) * HID + bn * 128 + lcol] =
              acc[m][n][r] + red[(lrow + r) * 132 + lcol];
      }
  }
}

// ---------------- pass B (MFMA): T_c = K^hat^T @ V (bf16 out), D_c = exp(cg_last) -------
__global__ __launch_bounds__(256) void gla_chunk_state2(const u16* __restrict__ Kb,
                                                        const u16* __restrict__ Vb,
                                                        const u16* __restrict__ CG,
                                                        u16* __restrict__ Tbuf,
                                                        float* __restrict__ Dbuf){
  __shared__ u16 KHT[64 * 72];
  __shared__ u16 VT[64 * 72];
  int blk = blockIdx.x;
  int c = blk & (NC - 1), bh = blk >> 5;
  int b = bh >> 4, h = bh & 15;
  int tid = threadIdx.x;
  int lane = tid & 63, w = tid >> 6;
  int lr = lane & 15, lk = lane >> 4;
  int tr = tid >> 2, tc = (tid & 3) * 16;
  size_t gbase = ((size_t)(b * L_SEQ + c * 64)) * HID + h * 64;

  float cg[16], cgl[16];
  {
    const u16* cgp = CG + gbase + (size_t)tr * HID + tc;
    const u16* clp = CG + gbase + (size_t)63 * HID + tc;
    uint4 a0 = *(const uint4*)cgp, a1 = *(const uint4*)(cgp + 8);
    uint4 l0 = *(const uint4*)clp, l1 = *(const uint4*)(clp + 8);
    const u16* au = (const u16*)&a0; const u16* au2 = (const u16*)&a1;
    const u16* lu = (const u16*)&l0; const u16* lu2 = (const u16*)&l1;
    #pragma unroll
    for (int e = 0; e < 8; e++){
      cg[e] = bf2f(au[e]); cg[8 + e] = bf2f(au2[e]);
      cgl[e] = bf2f(lu[e]); cgl[8 + e] = bf2f(lu2[e]);
    }
  }
  {
    const u16* kp = Kb + gbase + (size_t)tr * HID + tc;
    const u16* vp = Vb + gbase + (size_t)tr * HID + tc;
    uint4 kr0 = *(const uint4*)kp, kr1 = *(const uint4*)(kp + 8);
    uint4 vr0 = *(const uint4*)vp, vr1 = *(const uint4*)(vp + 8);
    const u16* ku = (const u16*)&kr0; const u16* ku2 = (const u16*)&kr1;
    const u16* vu = (const u16*)&vr0; const u16* vu2 = (const u16*)&vr1;
    #pragma unroll
    for (int e = 0; e < 8; e++){
      KHT[swz72(tc + e, tr)]     = f2bf(bf2f(ku[e])  * __expf(cgl[e]     - cg[e]));
      KHT[swz72(tc + 8 + e, tr)] = f2bf(bf2f(ku2[e]) * __expf(cgl[8 + e] - cg[8 + e]));
      VT[swz72(tc + e, tr)]      = vu[e];
      VT[swz72(tc + 8 + e, tr)]  = vu2[e];
    }
  }
  if (tr == 0){
    #pragma unroll
    for (int e = 0; e < 16; e++)
      Dbuf[(size_t)blk * 64 + tc + e] = __expf(cgl[e]);
  }
  __syncthreads();
  int R0 = w * 16;
  f32x4 tacc[4];
  #pragma unroll
  for (int v = 0; v < 4; v++)
    #pragma unroll
    for (int e = 0; e < 4; e++) tacc[v][e] = 0.f;
  #pragma unroll
  for (int ks = 0; ks < 2; ks++){
    bf16x8 a = *(const bf16x8*)&KHT[swz72(R0 + lr, ks * 32 + lk * 8)];
    #pragma unroll
    for (int v0 = 0; v0 < 4; v0++){
      bf16x8 bb = *(const bf16x8*)&VT[swz72(v0 * 16 + lr, ks * 32 + lk * 8)];
      tacc[v0] = __builtin_amdgcn_mfma_f32_16x16x32_bf16(a, bb, tacc[v0], 0, 0, 0);
    }
  }
  u16* Tp = Tbuf + (size_t)blk * 4096;
  #pragma unroll
  for (int v0 = 0; v0 < 4; v0++){
    int d = R0 + lk * 4, v = v0 * 16 + lr;
    #pragma unroll
    for (int r = 0; r < 4; r++)
      Tp[(d + r) * 64 + v] = f2bf(tacc[v0][r]);
  }
}

// ---------------- pass C: parallel chunk-state scan (bf16 T in, bf16 S_in out) ----------
__global__ __launch_bounds__(256) void gla_state_scan2(const u16* __restrict__ Tbuf,
                                                       const float* __restrict__ Dbuf,
                                                       float* __restrict__ Sfin,
                                                       u16* __restrict__ Sinb){
  int bh = blockIdx.x >> 4, seg = blockIdx.x & 15;
  int dv = seg * 256 + threadIdx.x;
  int d = dv >> 6;
  float S = 0.f;
  for (int c = 0; c < NC; c++){
    size_t slot = (size_t)bh * NC + c;
    float t  = bf2f(Tbuf[slot * 4096 + dv]);
    float dec = Dbuf[slot * 64 + d];
    Sinb[slot * 4096 + dv] = f2bf(S);
    S = dec * S + t;
  }
  Sfin[(size_t)bh * 4096 + dv] = S;
}

// ---------------- pass D (MFMA): outputs + RMSNorm + swish gate (3-barrier) ----------
__global__ __launch_bounds__(256) void gla_chunk_out2(const u16* __restrict__ Qb,
                                                      const u16* __restrict__ Kb,
                                                      const u16* __restrict__ Vb,
                                                      const u16* __restrict__ CG,
                                                      const u16* __restrict__ Sinb,
                                                      const u16* __restrict__ Gb,
                                                      const float* __restrict__ gnw,
                                                      u16* __restrict__ OG){
  __shared__ u16 QT[64 * 72];
  __shared__ u16 KP[64 * 72];
  __shared__ u16 VT[64 * 72];
  __shared__ u16 ST[64 * 72];
  int blk = blockIdx.x;
  int c = blk & (NC - 1), bh = blk >> 5;
  int b = bh >> 4, h = bh & 15;
  int tid = threadIdx.x;
  int lane = tid & 63, w = tid >> 6;
  int lr = lane & 15, lk = lane >> 4;
  int tr = tid >> 2, tc = (tid & 3) * 16;
  size_t gbase = ((size_t)(b * L_SEQ + c * 64)) * HID + h * 64;

  {
    float cg[16];
    const u16* cgp = CG + gbase + (size_t)tr * HID + tc;
    uint4 a0 = *(const uint4*)cgp, a1 = *(const uint4*)(cgp + 8);
    const u16* au = (const u16*)&a0; const u16* au2 = (const u16*)&a1;
    #pragma unroll
    for (int e = 0; e < 8; e++){ cg[e] = bf2f(au[e]); cg[8 + e] = bf2f(au2[e]); }
    const u16* qp = Qb + gbase + (size_t)tr * HID + tc;
    const u16* kp = Kb + gbase + (size_t)tr * HID + tc;
    const u16* vp = Vb + gbase + (size_t)tr * HID + tc;
    uint4 qr0 = *(const uint4*)qp, qr1 = *(const uint4*)(qp + 8);
    uint4 kr0 = *(const uint4*)kp, kr1 = *(const uint4*)(kp + 8);
    uint4 vr0 = *(const uint4*)vp, vr1 = *(const uint4*)(vp + 8);
    const u16* qu = (const u16*)&qr0; const u16* qu2 = (const u16*)&qr1;
    const u16* ku = (const u16*)&kr0; const u16* ku2 = (const u16*)&kr1;
    const u16* vu = (const u16*)&vr0; const u16* vu2 = (const u16*)&vr1;
    u16 qt[16] __attribute__((aligned(16)));
    u16 kt[16] __attribute__((aligned(16)));
    #pragma unroll
    for (int e = 0; e < 8; e++){
      float ec0 = __expf(cg[e]),  ei0 = __expf(-cg[e]);
      float ec1 = __expf(cg[8+e]), ei1 = __expf(-cg[8+e]);
      qt[e]     = f2bf(bf2f(qu[e])  * ec0 * QSCALE);
      qt[8 + e] = f2bf(bf2f(qu2[e]) * ec1 * QSCALE);
      kt[e]     = f2bf(bf2f(ku[e])  * ei0);
      kt[8 + e] = f2bf(bf2f(ku2[e]) * ei1);
      VT[swz72(tc + e, tr)]     = vu[e];
      VT[swz72(tc + 8 + e, tr)] = vu2[e];
    }
    *(uint4*)&QT[tr * 72 + tc]     = *(uint4*)&qt[0];
    *(uint4*)&QT[tr * 72 + tc + 8] = *(uint4*)&qt[8];
    *(uint4*)&KP[tr * 72 + tc]     = *(uint4*)&kt[0];
    *(uint4*)&KP[tr * 72 + tc + 8] = *(uint4*)&kt[8];
    const u16* sp = Sinb + (size_t)blk * 4096 + (size_t)tr * 64 + tc;
    uint4 s0 = *(const uint4*)sp, s1 = *(const uint4*)(sp + 8);
    const u16* su = (const u16*)&s0; const u16* su2 = (const u16*)&s1;
    #pragma unroll
    for (int e = 0; e < 8; e++){
      ST[swz72(tc + e, tr)]     = su[e];
      ST[swz72(tc + 8 + e, tr)] = su2[e];
    }
  }
  __syncthreads();

  int R0 = w * 16;
  f32x4 pacc[4];
  #pragma unroll
  for (int j = 0; j < 4; j++)
    #pragma unroll
    for (int e = 0; e < 4; e++) pacc[j][e] = 0.f;
  #pragma unroll
  for (int ks = 0; ks < 2; ks++){
    bf16x8 a = *(const bf16x8*)&QT[(R0 + lr) * 72 + ks * 32 + lk * 8];
    #pragma unroll
    for (int j0 = 0; j0 < 4; j0++){
      bf16x8 bb = *(const bf16x8*)&KP[(j0 * 16 + lr) * 72 + ks * 32 + lk * 8];
      pacc[j0] = __builtin_amdgcn_mfma_f32_16x16x32_bf16(a, bb, pacc[j0], 0, 0, 0);
    }
  }
  __syncthreads();

  #pragma unroll
  for (int j0 = 0; j0 < 4; j0++){
    int j = j0 * 16 + lr;
    #pragma unroll
    for (int r = 0; r < 4; r++){
      int t = R0 + lk * 4 + r;
      KP[t * 72 + (j ^ swzc(t))] = (j <= t) ? f2bf(pacc[j0][r]) : (u16)0;
    }
  }

  f32x4 oacc[4];
  #pragma unroll
  for (int v = 0; v < 4; v++)
    #pragma unroll
    for (int e = 0; e < 4; e++) oacc[v][e] = 0.f;
  #pragma unroll
  for (int ks = 0; ks < 2; ks++){
    bf16x8 a = *(const bf16x8*)&QT[(R0 + lr) * 72 + ks * 32 + lk * 8];
    #pragma unroll
    for (int v0 = 0; v0 < 4; v0++){
      bf16x8 bb = *(const bf16x8*)&ST[swz72(v0 * 16 + lr, ks * 32 + lk * 8)];
      oacc[v0] = __builtin_amdgcn_mfma_f32_16x16x32_bf16(a, bb, oacc[v0], 0, 0, 0);
    }
  }
  #pragma unroll
  for (int ks = 0; ks < 2; ks++){
    int arow = R0 + lr;
    bf16x8 a = *(const bf16x8*)&KP[arow * 72 + ((ks * 32 + lk * 8) ^ swzc(arow))];
    #pragma unroll
    for (int v0 = 0; v0 < 4; v0++){
      bf16x8 bb = *(const bf16x8*)&VT[swz72(v0 * 16 + lr, ks * 32 + lk * 8)];
      oacc[v0] = __builtin_amdgcn_mfma_f32_16x16x32_bf16(a, bb, oacc[v0], 0, 0, 0);
    }
  }

  {
    float gv[4][4];
    #pragma unroll
    for (int r = 0; r < 4; r++){
      int t = R0 + lk * 4 + r;
      #pragma unroll
      for (int v0 = 0; v0 < 4; v0++)
        gv[r][v0] = bf2f(Gb[gbase + (size_t)t * HID + v0 * 16 + lr]);
    }
    float gnv[4];
    #pragma unroll
    for (int v0 = 0; v0 < 4; v0++) gnv[v0] = gnw[v0 * 16 + lr];
    #pragma unroll
    for (int r = 0; r < 4; r++){
      float ssq = 0.f;
      #pragma unroll
      for (int v0 = 0; v0 < 4; v0++) ssq += oacc[v0][r] * oacc[v0][r];
      ssq += __shfl_xor(ssq, 1, 64);
      ssq += __shfl_xor(ssq, 2, 64);
      ssq += __shfl_xor(ssq, 4, 64);
      ssq += __shfl_xor(ssq, 8, 64);
      float rn = rsqrtf(ssq * (1.0f / 64.0f) + GEPS);
      int t = R0 + lk * 4 + r;
      #pragma unroll
      for (int v0 = 0; v0 < 4; v0++){
        float g = gv[r][v0];
        float sw = g / (1.f + __expf(-g));
        QT[t * 72 + ((v0 * 16 + lr) ^ swzc(t))] = f2bf(oacc[v0][r] * rn * gnv[v0] * sw);
      }
    }
  }
  __syncthreads();
  {
    int x0 = swzc(tr);
    uint4 o0 = *(uint4*)&QT[tr * 72 + (tc ^ x0)];
    uint4 o1 = *(uint4*)&QT[tr * 72 + ((tc + 8) ^ x0)];
    u16* op = OG + gbase + (size_t)tr * HID + tc;
    *(uint4*)op       = o0;
    *(uint4*)(op + 8) = o1;
  }
}

// ---------------- host launcher ----------------
extern "C" void kernel_launch(void* const* d_in, const int* in_sizes, int n_in,
                              void* d_out, int out_size, void* d_ws, size_t ws_size,
                              hipStream_t stream){
  (void)in_sizes; (void)n_in; (void)out_size;
  const float* x   = (const float*)d_in[0];
  const float* Wq  = (const float*)d_in[1];
  const float* Wk  = (const float*)d_in[2];
  const float* Wv  = (const float*)d_in[3];
  const float* Wg1 = (const float*)d_in[4];
  const float* Wg2 = (const float*)d_in[5];
  const float* bg2 = (const float*)d_in[6];
  const float* Wg  = (const float*)d_in[7];
  const float* gnw = (const float*)d_in[8];
  const float* Wo  = (const float*)d_in[9];
  float* out = (float*)d_out;

  char* ws = (char*)d_ws;
  size_t off = 0;
  auto alloc = [&](size_t bytes) -> char* {
    char* p = ws + off; off += (bytes + 255) & ~(size_t)255; return p;
  };
  u16* xb   = (u16*)alloc((size_t)MTOK * HID * 2);
  u16* WTq  = (u16*)alloc((size_t)HID * HID * 2);   // WTq..WTg contiguous: combined N=4096
  u16* WTk  = (u16*)alloc((size_t)HID * HID * 2);
  u16* WTv  = (u16*)alloc((size_t)HID * HID * 2);
  u16* WTg  = (u16*)alloc((size_t)HID * HID * 2);
  u16* WTo  = (u16*)alloc((size_t)HID * HID * 2);
  u16* Qb   = (u16*)alloc((size_t)MTOK * HID * 2);  // Qb..Gb contiguous: sel-strided C
  u16* Kb   = (u16*)alloc((size_t)MTOK * HID * 2);
  u16* Vb   = (u16*)alloc((size_t)MTOK * HID * 2);
  u16* Gb   = (u16*)alloc((size_t)MTOK * HID * 2);
  u16* CGb  = (u16*)alloc((size_t)MTOK * HID * 2);
  float* xg1b = (float*)alloc((size_t)MTOK * 16 * 4);
  u16* Tbuf = (u16*)alloc((size_t)1024 * 4096 * 2);
  float* Dbuf = (float*)alloc((size_t)1024 * 64 * 4);
  u16* Sinb = (u16*)alloc((size_t)1024 * 4096 * 2);
  u16* OG   = (u16*)alloc((size_t)MTOK * HID * 2);
  if (off > ws_size) return;

  gla_prep<<<7168, 256, 0, stream>>>(x, xb, Wq, Wk, Wv, Wg, Wo,
                                     WTq, WTk, WTv, WTg, WTo);
  gla_xg1_mfma<<<64, 256, 0, stream>>>(xb, Wg1, xg1b);
  gla_gkcg<<<256, 256, 0, stream>>>(xg1b, Wg2, bg2, CGb);

  dim3 gq(16, 32);
  gla_gemm_qkvg<<<gq, 512, 0, stream>>>(xb, WTq, Qb);   // Q,K,V,G in one dispatch

  gla_chunk_state2<<<1024, 256, 0, stream>>>(Kb, Vb, CGb, Tbuf, Dbuf);
  gla_state_scan2<<<512, 256, 0, stream>>>(Tbuf, Dbuf, out + (size_t)MTOK * HID, Sinb);
  gla_chunk_out2<<<1024, 256, 0, stream>>>(Qb, Kb, Vb, CGb, Sinb, Gb, gnw, OG);

  dim3 go(64, 8);
  gla_gemm_out2<<<go, 256, 0, stream>>>(OG, WTo, out);
}